// Round 12
// baseline (143.152 us; speedup 1.0000x reference)
//
#include <hip/hip_runtime.h>
#include <hip/hip_bf16.h>

// Shapes (fixed by the problem)
#define NB   16    // batch
#define NC   512   // channels
#define NSPA 1024  // h*w
#define GN_EPS 1e-5f
#define SCL 0.044194173824159216f  // 512^-0.5

typedef __bf16 bf16x8 __attribute__((ext_vector_type(8)));
typedef __bf16 bf16x4 __attribute__((ext_vector_type(4)));
typedef float  f32x4  __attribute__((ext_vector_type(4)));

typedef __attribute__((address_space(3))) void lds_t;
typedef const __attribute__((address_space(1))) void gl_t;
#define GLDS16(g, l) __builtin_amdgcn_global_load_lds((gl_t*)(g), (lds_t*)(l), 16, 0, 0)

__device__ __forceinline__ __bf16 tob(float f) { return (__bf16)f; }

// Bijective XCD-chunk swizzle (T1): each XCD gets a contiguous logical chunk.
__device__ __forceinline__ int xcd_swz(int cpx) {
  return (blockIdx.x & 7) * cpx + (blockIdx.x >> 3);
}

// ===========================================================================
// K1: prep — one launch, heterogeneous blocks (grid 788):
//   id <  512 : fused GroupNorm + transpose -> xnT[b][n][c] bf16.
//               TWO-PASS: pass1 accumulates s/ss only (NO register caching —
//               r11's float4 vv[16] was 64 VGPRs and spilled to scratch,
//               46 us); pass2 re-reads the block's 64KB chunk (L2-hot) and
//               writes the LDS-transposed bf16.
//   id <  704 : 64x64 transpose tiles wqT/wkT/wvT[c][o] bf16  (192 blocks)
//   id <  768 : pack Wout natural -> wob bf16                  (64 blocks)
//   id <  776 : rvec[c] = sum_o Wk[o][c]*bq[o]                 (8 blocks)
//   id <  784 : bc[o]   = sum_c Wout[o][c]*bv[c]               (8 blocks)
//   id <  788 : zero rowsum[16384] (re-zero every call)        (4 blocks)
// ===========================================================================
__global__ void prep_kernel(const float* __restrict__ x,
                            const float* __restrict__ gn_scale,
                            const float* __restrict__ gn_bias,
                            const float* __restrict__ wq,   // w_qkv [1536][512]
                            const float* __restrict__ wo,   // w_out [512][512]
                            const float* __restrict__ bqkv, // [1536]
                            __bf16* __restrict__ xnT, __bf16* __restrict__ wqT,
                            __bf16* __restrict__ wkT, __bf16* __restrict__ wvT,
                            __bf16* __restrict__ wob, float* __restrict__ rvec,
                            float* __restrict__ bc, float* __restrict__ rowsum) {
  __shared__ __align__(16) unsigned char smem[37120];
  const int id = blockIdx.x;
  const int t = threadIdx.x;
  if (id < 512) {
    const int L = (id & 7) * 64 + (id >> 3);   // XCD-chunk swizzle (CPX=64)
    const int b = L >> 5, g = L & 31;
    const int row = t >> 4, sub = t & 15;
    const float4* bx = (const float4*)(x + (size_t)(b * NC + g * 16 + row) * NSPA);
    // pass 1: stats only (no data caching -> no spill)
    float s = 0.f, ss = 0.f;
#pragma unroll
    for (int k = 0; k < 16; ++k) {
      float4 v = bx[sub + k * 16];
      s  += (v.x + v.y) + (v.z + v.w);
      ss += (v.x * v.x + v.y * v.y) + (v.z * v.z + v.w * v.w);
    }
#pragma unroll
    for (int off = 32; off; off >>= 1) { s += __shfl_xor(s, off); ss += __shfl_xor(ss, off); }
    float* red = (float*)(smem + 36864);
    const int wave = t >> 6, lane = t & 63;
    if (lane == 0) { red[wave] = s; red[4 + wave] = ss; }
    __syncthreads();
    const float S  = red[0] + red[1] + red[2] + red[3];
    const float SS = red[4] + red[5] + red[6] + red[7];
    const float mean = S * (1.f / 16384.f);
    const float var  = SS * (1.f / 16384.f) - mean * mean;
    const float rstd = rsqrtf(var + GN_EPS);
    const int c = g * 16 + row;
    const float a  = gn_scale[c] * rstd;
    const float bb = gn_bias[c] - mean * a;
    // pass 2: re-read (L2-hot) -> LDS transpose
    __bf16 (*lt)[18] = (__bf16(*)[18])smem;   // [1024][16+2pad] bf16
#pragma unroll
    for (int k = 0; k < 16; ++k) {
      float4 v = bx[sub + k * 16];
      const int n0 = (sub + k * 16) * 4;
      lt[n0 + 0][row] = tob(v.x * a + bb);
      lt[n0 + 1][row] = tob(v.y * a + bb);
      lt[n0 + 2][row] = tob(v.z * a + bb);
      lt[n0 + 3][row] = tob(v.w * a + bb);
    }
    __syncthreads();
#pragma unroll
    for (int r = 0; r < 4; ++r) {
      const int n = t * 4 + r;
      const unsigned int* lr = (const unsigned int*)&lt[n][0];
      uint4 d0, d1;
      d0.x = lr[0]; d0.y = lr[1]; d0.z = lr[2]; d0.w = lr[3];
      d1.x = lr[4]; d1.y = lr[5]; d1.z = lr[6]; d1.w = lr[7];
      uint4* dst = (uint4*)(xnT + (size_t)(b * NSPA + n) * NC + g * 16);
      dst[0] = d0; dst[1] = d1;
    }
  } else if (id < 704) {
    const int id2 = id - 512;
    const int mat = id2 >> 6, tile = id2 & 63;
    const int o0 = (tile >> 3) * 64, c0 = (tile & 7) * 64;
    __bf16* dstT = (mat == 0) ? wqT : (mat == 1) ? wkT : wvT;
    __bf16 (*l)[72] = (__bf16(*)[72])smem;
    const int orr = t >> 2, seg = (t & 3) * 16;
    const float4* src = (const float4*)(wq + (size_t)(mat * NC + o0 + orr) * NC + c0 + seg);
#pragma unroll
    for (int i = 0; i < 4; ++i) {
      float4 v = src[i];
      l[seg + i * 4 + 0][orr] = tob(v.x);
      l[seg + i * 4 + 1][orr] = tob(v.y);
      l[seg + i * 4 + 2][orr] = tob(v.z);
      l[seg + i * 4 + 3][orr] = tob(v.w);
    }
    __syncthreads();
#pragma unroll
    for (int i = 0; i < 2; ++i) {
      const int chunk = t + i * 256;
      const int row = chunk >> 3, sg = chunk & 7;
      *(bf16x8*)(dstT + (size_t)(c0 + row) * NC + o0 + sg * 8) = *(const bf16x8*)&l[row][sg * 8];
    }
  } else if (id < 768) {
    const int idx = id - 704;
#pragma unroll
    for (int i = 0; i < 4; ++i) {
      const int tt = idx * 1024 + i * 256 + t;
      float4 v = ((const float4*)wo)[tt];
      bf16x4 w;
      w[0] = tob(v.x); w[1] = tob(v.y); w[2] = tob(v.z); w[3] = tob(v.w);
      *(bf16x4*)(wob + (size_t)tt * 4) = w;
    }
  } else if (id < 776) {
    const int c0 = (id - 768) * 64;
    const int lane = t & 63, wave = t >> 6;
    const int c = c0 + lane;
    float s = 0.f;
    for (int o = wave * 128; o < wave * 128 + 128; ++o)
      s += wq[(size_t)(NC + o) * NC + c] * bqkv[o];
    float* red = (float*)smem;
    red[wave * 64 + lane] = s;
    __syncthreads();
    if (wave == 0) {
      float tot = red[lane] + red[64 + lane] + red[128 + lane] + red[192 + lane];
      rvec[c] = tot;
    }
  } else if (id < 784) {
    const int o = (id - 776) * 64 + (t >> 2);
    const int q = t & 3;
    const float4* wr = (const float4*)(wo + (size_t)o * NC + q * 128);
    const float4* bv = (const float4*)(bqkv + 2 * NC + q * 128);
    float s = 0.f;
#pragma unroll
    for (int i = 0; i < 32; ++i) {
      float4 w4 = wr[i], b4 = bv[i];
      s += (w4.x * b4.x + w4.y * b4.y) + (w4.z * b4.z + w4.w * b4.w);
    }
    s += __shfl_xor(s, 1);
    s += __shfl_xor(s, 2);
    if (q == 0) bc[o] = s;
  } else {
    // zero rowsum: 4 blocks x 4096 floats
    float4* dst = (float4*)(rowsum + (id - 784) * 4096);
#pragma unroll
    for (int i = 0; i < 4; ++i) dst[i * 256 + t] = make_float4(0.f, 0.f, 0.f, 0.f);
  }
}

// ---------------------------------------------------------------------------
// r3 2-phase 128^2 BK=64 core (proven): XOR-swizzled LDS (0 conflicts),
// dbuf, setprio.
// ---------------------------------------------------------------------------
__device__ __forceinline__ void stage_pair(const __bf16* __restrict__ A, int lda,
                                           const __bf16* __restrict__ B, int ldb,
                                           int k0, __bf16* lAf, __bf16* lBf) {
  const int tid = threadIdx.x;
#pragma unroll
  for (int i = 0; i < 4; ++i) {
    const int idx = tid + i * 256;
    const int srow = idx >> 3;
    const int ss = ((idx & 7) ^ (srow & 7)) * 8;
    GLDS16(A + (size_t)srow * lda + k0 + ss, lAf + idx * 8);
    GLDS16(B + (size_t)srow * ldb + k0 + ss, lBf + idx * 8);
  }
}

__device__ __forceinline__ void gemm_core_db(const __bf16* __restrict__ A, int lda,
                                             const __bf16* __restrict__ B, int ldb,
                                             int K, __bf16 (*lA)[128][64],
                                             __bf16 (*lB)[128][64], f32x4 acc[4][4]) {
  const int tid = threadIdx.x;
  const int lane = tid & 63, wave = tid >> 6;
  const int wm = (wave >> 1) * 64, wn = (wave & 1) * 64;
  const int fr = lane & 15, fg = (lane >> 4) * 8;
  const int nt = K >> 6;

  stage_pair(A, lda, B, ldb, 0, &lA[0][0][0], &lB[0][0][0]);
  asm volatile("s_waitcnt vmcnt(0)" ::: "memory");
  __syncthreads();
  int cur = 0;
  for (int t = 0; t < nt; ++t) {
    if (t + 1 < nt)
      stage_pair(A, lda, B, ldb, (t + 1) * 64, &lA[cur ^ 1][0][0], &lB[cur ^ 1][0][0]);
    __builtin_amdgcn_s_setprio(1);
#pragma unroll
    for (int ks = 0; ks < 2; ++ks) {
      bf16x8 af[4], bfr[4];
#pragma unroll
      for (int mi = 0; mi < 4; ++mi) {
        const int r = wm + mi * 16 + fr;
        af[mi] = *(const bf16x8*)&lA[cur][r][(ks * 32 + fg) ^ ((r & 7) << 3)];
      }
#pragma unroll
      for (int ni = 0; ni < 4; ++ni) {
        const int r = wn + ni * 16 + fr;
        bfr[ni] = *(const bf16x8*)&lB[cur][r][(ks * 32 + fg) ^ ((r & 7) << 3)];
      }
#pragma unroll
      for (int mi = 0; mi < 4; ++mi)
#pragma unroll
        for (int ni = 0; ni < 4; ++ni)
          acc[mi][ni] = __builtin_amdgcn_mfma_f32_16x16x32_bf16(af[mi], bfr[ni], acc[mi][ni], 0, 0, 0);
    }
    __builtin_amdgcn_s_setprio(0);
    if (t + 1 < nt) {
      asm volatile("s_waitcnt vmcnt(0)" ::: "memory");
      __syncthreads();
      cur ^= 1;
    }
  }
}

// ===========================================================================
// K2: mid — one launch (grid 288): id<32 small GEMMs -> Aproj; id>=32 R.
// ===========================================================================
__global__ __launch_bounds__(256, 2) void mid_kernel(
    const __bf16* __restrict__ wqT, const __bf16* __restrict__ wkT,
    const __bf16* __restrict__ wvT, const __bf16* __restrict__ wob,
    const __bf16* __restrict__ xnT, const float* __restrict__ rvec,
    __bf16* __restrict__ Aproj, float* __restrict__ R) {
  __shared__ __bf16 lA[2][128][64], lB[2][128][64];
  const int id = blockIdx.x;
  if (id < 32) {
    const bool doM = id < 16;
    const int sub = doM ? id : id - 16;
    const int mt = sub >> 2, nt2 = sub & 3;
    const __bf16* A = doM ? (wqT + (size_t)mt * 128 * NC) : (wob + (size_t)mt * 128 * NC);
    const __bf16* B = doM ? (wkT + (size_t)nt2 * 128 * NC) : (wvT + (size_t)nt2 * 128 * NC);
    f32x4 acc[4][4] = {};
    gemm_core_db(A, NC, B, NC, NC, lA, lB, acc);

    const int tid = threadIdx.x;
    const int lane = tid & 63, wave = tid >> 6;
    const int wm = (wave >> 1) * 64, wn = (wave & 1) * 64;
    const int fr = lane & 15, fq4 = (lane >> 4) * 4;
    const int mbase = (doM ? 0 : NC) + mt * 128;
#pragma unroll
    for (int mi = 0; mi < 4; ++mi) {
      const int m = mbase + wm + mi * 16 + fq4;
#pragma unroll
      for (int ni = 0; ni < 4; ++ni) {
        const int n = nt2 * 128 + wn + ni * 16 + fr;
#pragma unroll
        for (int r = 0; r < 4; ++r)
          Aproj[(size_t)(m + r) * NC + n] = tob(acc[mi][ni][r]);
      }
    }
  } else {
    const int id2 = id - 32;
    const int L = (id2 & 7) * 32 + (id2 >> 3);  // CPX=32 -> XCD=b/2
    const int b = L >> 4, j0 = (L & 15) * 64;
    const int row = threadIdx.x >> 2, q = threadIdx.x & 3;
    const __bf16* src = xnT + ((size_t)(b * NSPA) + j0 + row) * NC + q * 128;
    const float* rv = rvec + q * 128;
    float s = 0.f;
#pragma unroll
    for (int i = 0; i < 16; ++i) {
      bf16x8 v = *(const bf16x8*)(src + i * 8);
#pragma unroll
      for (int e = 0; e < 8; ++e) s += (float)v[e] * rv[i * 8 + e];
    }
    s += __shfl_xor(s, 1);
    s += __shfl_xor(s, 2);
    if (q == 0) R[b * NSPA + j0 + row] = s;
  }
}

// ---------------------------------------------------------------------------
// K3: proj GEMM. C[m][n=(b,j)] = Aproj[m][:] . xn_j
//   m <  512: transposed store -> Yt[b][j][c]
//   m >= 512: natural store -> v'[b][d][j] + bc[d]
// grid 1024 (CPX=128 -> XCD=b/2)
// ---------------------------------------------------------------------------
__global__ __launch_bounds__(256, 2) void proj_kernel(
    const __bf16* __restrict__ Aproj, const __bf16* __restrict__ xnT,
    const float* __restrict__ bc, __bf16* __restrict__ Yt, __bf16* __restrict__ vp) {
  const int L = xcd_swz(128);
  const int pair = L >> 3, mblk = L & 7;
  const int b = pair >> 3;
  const int n0 = (pair & 7) * 128, m0 = mblk * 128;
  __shared__ __bf16 lA[2][128][64], lB[2][128][64];
  f32x4 acc[4][4] = {};
  gemm_core_db(Aproj + (size_t)m0 * NC, NC, xnT + ((size_t)b * NSPA + n0) * NC, NC,
               NC, lA, lB, acc);

  const int lane = threadIdx.x & 63, wave = threadIdx.x >> 6;
  const int wm = (wave >> 1) * 64, wn = (wave & 1) * 64;
  const int fr = lane & 15, fq4 = (lane >> 4) * 4;
  if (m0 < NC) {  // Y path: transposed store
#pragma unroll
    for (int mi = 0; mi < 4; ++mi) {
      const int m = m0 + wm + mi * 16 + fq4;
#pragma unroll
      for (int ni = 0; ni < 4; ++ni) {
        const int n = n0 + wn + ni * 16 + fr;
        bf16x4 w;
        w[0] = tob(acc[mi][ni][0]);
        w[1] = tob(acc[mi][ni][1]);
        w[2] = tob(acc[mi][ni][2]);
        w[3] = tob(acc[mi][ni][3]);
        *(bf16x4*)(Yt + ((size_t)b * NSPA + n) * NC + m) = w;
      }
    }
  } else {  // v' path: natural store + bc
#pragma unroll
    for (int mi = 0; mi < 4; ++mi) {
      const int m = m0 + wm + mi * 16 + fq4;
      const int d = m - NC;
      const float4 bias = *(const float4*)(bc + d);
#pragma unroll
      for (int ni = 0; ni < 4; ++ni) {
        const int n = n0 + wn + ni * 16 + fr;
        vp[((size_t)b * NC + d + 0) * NSPA + n] = tob(acc[mi][ni][0] + bias.x);
        vp[((size_t)b * NC + d + 1) * NSPA + n] = tob(acc[mi][ni][1] + bias.y);
        vp[((size_t)b * NC + d + 2) * NSPA + n] = tob(acc[mi][ni][2] + bias.z);
        vp[((size_t)b * NC + d + 3) * NSPA + n] = tob(acc[mi][ni][3] + bias.w);
      }
    }
  }
}

// ---------------------------------------------------------------------------
// K4: scores + exp + rowsum (softmax pass deleted; unnormalized exp).
// grid 1024 (CPX=128 -> XCD=b/2)
// ---------------------------------------------------------------------------
__global__ __launch_bounds__(256, 2) void scores_kernel(
    const __bf16* __restrict__ Yt, const __bf16* __restrict__ xnT,
    const float* __restrict__ R, __bf16* __restrict__ P,
    float* __restrict__ rowsum) {
  const int L = xcd_swz(128);
  const int b = L >> 6, r = L & 63;
  const int i0 = (r >> 3) * 128, j0 = (r & 7) * 128;
  __shared__ __bf16 lA[2][128][64], lB[2][128][64];
  f32x4 acc[4][4] = {};
  gemm_core_db(Yt + ((size_t)b * NSPA + j0) * NC, NC,
               xnT + ((size_t)b * NSPA + i0) * NC, NC, NC, lA, lB, acc);

  const int lane = threadIdx.x & 63, wave = threadIdx.x >> 6;
  const int wm = (wave >> 1) * 64, wn = (wave & 1) * 64;
  const int fr = lane & 15, fq4 = (lane >> 4) * 4;
  float rsum[4] = {0.f, 0.f, 0.f, 0.f};
#pragma unroll
  for (int mi = 0; mi < 4; ++mi) {
    const int j = j0 + wm + mi * 16 + fq4;
    const float4 Rb = *(const float4*)(R + b * NSPA + j);
#pragma unroll
    for (int ni = 0; ni < 4; ++ni) {
      const int i = i0 + wn + ni * 16 + fr;
      bf16x4 w;
      w[0] = tob(__expf((acc[mi][ni][0] + Rb.x) * SCL));
      w[1] = tob(__expf((acc[mi][ni][1] + Rb.y) * SCL));
      w[2] = tob(__expf((acc[mi][ni][2] + Rb.z) * SCL));
      w[3] = tob(__expf((acc[mi][ni][3] + Rb.w) * SCL));
      rsum[ni] += ((float)w[0] + (float)w[1]) + ((float)w[2] + (float)w[3]);
      *(bf16x4*)(P + ((size_t)b * NSPA + i) * NSPA + j) = w;
    }
  }
#pragma unroll
  for (int ni = 0; ni < 4; ++ni) {
    rsum[ni] += __shfl_xor(rsum[ni], 16);
    rsum[ni] += __shfl_xor(rsum[ni], 32);
  }
  if (lane < 16) {
#pragma unroll
    for (int ni = 0; ni < 4; ++ni)
      atomicAdd(&rowsum[b * NSPA + i0 + wn + ni * 16 + fr], rsum[ni]);
  }
}

// ---------------------------------------------------------------------------
// K5: PV + normalize + out fused. out = C/rowsum + bout + x (fp32).
// grid 512 (CPX=64 -> XCD=b/2)
// ---------------------------------------------------------------------------
__global__ __launch_bounds__(256, 2) void pvout_kernel(
    const __bf16* __restrict__ vp, const __bf16* __restrict__ P,
    const float* __restrict__ rowsum, const float* __restrict__ bout,
    const float* __restrict__ x, float* __restrict__ out) {
  const int L = xcd_swz(64);
  const int b = L >> 5, r = L & 31;
  const int d0 = (r >> 3) * 128, i0 = (r & 7) * 128;
  __shared__ __bf16 lA[2][128][64], lB[2][128][64];
  f32x4 acc[4][4] = {};
  gemm_core_db(vp + ((size_t)b * NC + d0) * NSPA, NSPA,
               P + ((size_t)b * NSPA + i0) * NSPA, NSPA, NSPA, lA, lB, acc);

  const int lane = threadIdx.x & 63, wave = threadIdx.x >> 6;
  const int wm = (wave >> 1) * 64, wn = (wave & 1) * 64;
  const int fr = lane & 15, fq4 = (lane >> 4) * 4;
  float inv[4];
#pragma unroll
  for (int ni = 0; ni < 4; ++ni)
    inv[ni] = 1.f / rowsum[b * NSPA + i0 + wn + ni * 16 + fr];
#pragma unroll
  for (int mi = 0; mi < 4; ++mi) {
    const int d = d0 + wm + mi * 16 + fq4;
    const float4 bias = *(const float4*)(bout + d);
#pragma unroll
    for (int ni = 0; ni < 4; ++ni) {
      const int i = i0 + wn + ni * 16 + fr;
      const size_t ix = ((size_t)b * NC + d) * NSPA + i;
      out[ix + 0 * NSPA] = acc[mi][ni][0] * inv[ni] + bias.x + x[ix + 0 * NSPA];
      out[ix + 1 * NSPA] = acc[mi][ni][1] * inv[ni] + bias.y + x[ix + 1 * NSPA];
      out[ix + 2 * NSPA] = acc[mi][ni][2] * inv[ni] + bias.z + x[ix + 2 * NSPA];
      out[ix + 3 * NSPA] = acc[mi][ni][3] * inv[ni] + bias.w + x[ix + 3 * NSPA];
    }
  }
}

// ---------------------------------------------------------------------------
// Workspace (~67 MB):
//   rvec/bc 4KB | R 64KB | rowsum 64KB | wqT/wkT/wvT/wob 2MB | Aproj 1MB
//   xnT 16MB | v' 16MB | P 32MB.   Yt (16MB) lives in d_out (dead til pvout).
// ---------------------------------------------------------------------------
extern "C" void kernel_launch(void* const* d_in, const int* in_sizes, int n_in,
                              void* d_out, int out_size, void* d_ws, size_t ws_size,
                              hipStream_t stream) {
  const float* x        = (const float*)d_in[0];
  const float* gn_scale = (const float*)d_in[3];
  const float* gn_bias  = (const float*)d_in[4];
  const float* w_qkv    = (const float*)d_in[5];
  const float* b_qkv    = (const float*)d_in[6];
  const float* w_out    = (const float*)d_in[7];
  const float* b_out    = (const float*)d_in[8];
  float* out = (float*)d_out;

  float*  rvec   = (float*)d_ws;                 // 512
  float*  bc     = rvec + NC;                    // 512
  float*  R      = bc + NC;                      // 16384
  float*  rowsum = R + NB * NSPA;                // 16384
  __bf16* wqT    = (__bf16*)(rowsum + NB * NSPA);
  __bf16* wkT    = wqT + NC * NC;
  __bf16* wvT    = wkT + NC * NC;
  __bf16* wob    = wvT + NC * NC;
  __bf16* Aproj  = wob + NC * NC;                // 1024x512
  __bf16* xnT    = Aproj + 2 * NC * NC;          // 8M elems
  __bf16* vp     = xnT + (size_t)NB * NSPA * NC; // 8M elems
  __bf16* P      = vp + (size_t)NB * NC * NSPA;  // 16M elems
  __bf16* Yt     = (__bf16*)d_out;               // 16MB scratch in d_out

  prep_kernel<<<dim3(788), 256, 0, stream>>>(x, gn_scale, gn_bias, w_qkv, w_out,
                                             b_qkv, xnT, wqT, wkT, wvT, wob, rvec,
                                             bc, rowsum);
  mid_kernel<<<dim3(288), 256, 0, stream>>>(wqT, wkT, wvT, wob, xnT, rvec, Aproj, R);
  proj_kernel<<<dim3(1024), 256, 0, stream>>>(Aproj, xnT, bc, Yt, vp);
  scores_kernel<<<dim3(1024), 256, 0, stream>>>(Yt, xnT, R, P, rowsum);
  pvout_kernel<<<dim3(512), 256, 0, stream>>>(vp, P, rowsum, b_out, x, out);
}

// Round 13
// 124.171 us; speedup vs baseline: 1.1529x; 1.1529x over previous
//
#include <hip/hip_runtime.h>
#include <hip/hip_bf16.h>

// Shapes (fixed by the problem)
#define NB   16    // batch
#define NC   512   // channels
#define NSPA 1024  // h*w
#define GN_EPS 1e-5f
#define SCL 0.044194173824159216f  // 512^-0.5

typedef __bf16 bf16x8 __attribute__((ext_vector_type(8)));
typedef __bf16 bf16x4 __attribute__((ext_vector_type(4)));
typedef float  f32x4  __attribute__((ext_vector_type(4)));

typedef __attribute__((address_space(3))) void lds_t;
typedef const __attribute__((address_space(1))) void gl_t;
#define GLDS16(g, l) __builtin_amdgcn_global_load_lds((gl_t*)(g), (lds_t*)(l), 16, 0, 0)

__device__ __forceinline__ __bf16 tob(float f) { return (__bf16)f; }

// Bijective XCD-chunk swizzle (T1): each XCD gets a contiguous logical chunk.
__device__ __forceinline__ int xcd_swz(int cpx) {
  return (blockIdx.x & 7) * cpx + (blockIdx.x >> 3);
}

// ===========================================================================
// K1: stats_w — lightweight heterogeneous blocks (grid 788):
//   id <  512 : GN stats ONLY -> coefA/coefB (pass-2 moved to pack_x, which
//               runs at 8 blocks/CU instead of 2 — r12's fused prep was
//               latency-bound at 47 us)
//   id <  704 : 64x64 transpose tiles wqT/wkT/wvT[c][o] bf16  (192 blocks)
//   id <  768 : pack Wout natural -> wob bf16                  (64 blocks)
//   id <  776 : rvec[c] = sum_o Wk[o][c]*bq[o]                 (8 blocks)
//   id <  784 : bc[o]   = sum_c Wout[o][c]*bv[c]               (8 blocks)
//   id <  788 : zero rowsum[16384] (re-zero every call)        (4 blocks)
// ===========================================================================
__global__ void stats_w_kernel(const float* __restrict__ x,
                               const float* __restrict__ gn_scale,
                               const float* __restrict__ gn_bias,
                               const float* __restrict__ wq,   // w_qkv [1536][512]
                               const float* __restrict__ wo,   // w_out [512][512]
                               const float* __restrict__ bqkv, // [1536]
                               float* __restrict__ coefA, float* __restrict__ coefB,
                               __bf16* __restrict__ wqT, __bf16* __restrict__ wkT,
                               __bf16* __restrict__ wvT, __bf16* __restrict__ wob,
                               float* __restrict__ rvec, float* __restrict__ bc,
                               float* __restrict__ rowsum) {
  __shared__ __align__(16) unsigned char smem[9216];
  const int id = blockIdx.x;
  const int t = threadIdx.x;
  if (id < 512) {
    const int L = (id & 7) * 64 + (id >> 3);   // XCD-chunk swizzle (CPX=64)
    const int b = L >> 5, g = L & 31;
    const float4* base = (const float4*)(x + (size_t)(b * NC + g * 16) * NSPA);
    float s = 0.f, ss = 0.f;
#pragma unroll
    for (int i = 0; i < 16; ++i) {
      float4 v = base[i * 256 + t];
      s  += (v.x + v.y) + (v.z + v.w);
      ss += (v.x * v.x + v.y * v.y) + (v.z * v.z + v.w * v.w);
    }
#pragma unroll
    for (int off = 32; off; off >>= 1) {
      s  += __shfl_xor(s, off);
      ss += __shfl_xor(ss, off);
    }
    float* red = (float*)smem;
    const int wave = t >> 6, lane = t & 63;
    if (lane == 0) { red[wave] = s; red[4 + wave] = ss; }
    __syncthreads();
    if (t < 16) {
      const float S  = red[0] + red[1] + red[2] + red[3];
      const float SS = red[4] + red[5] + red[6] + red[7];
      const float mean = S * (1.f / 16384.f);
      const float var  = SS * (1.f / 16384.f) - mean * mean;
      const float rstd = rsqrtf(var + GN_EPS);
      const int c = g * 16 + t;
      const float a = gn_scale[c] * rstd;
      coefA[b * NC + c] = a;
      coefB[b * NC + c] = gn_bias[c] - mean * a;
    }
  } else if (id < 704) {
    const int id2 = id - 512;
    const int mat = id2 >> 6, tile = id2 & 63;
    const int o0 = (tile >> 3) * 64, c0 = (tile & 7) * 64;
    __bf16* dstT = (mat == 0) ? wqT : (mat == 1) ? wkT : wvT;
    __bf16 (*l)[72] = (__bf16(*)[72])smem;
    const int orr = t >> 2, seg = (t & 3) * 16;
    const float4* src = (const float4*)(wq + (size_t)(mat * NC + o0 + orr) * NC + c0 + seg);
#pragma unroll
    for (int i = 0; i < 4; ++i) {
      float4 v = src[i];
      l[seg + i * 4 + 0][orr] = tob(v.x);
      l[seg + i * 4 + 1][orr] = tob(v.y);
      l[seg + i * 4 + 2][orr] = tob(v.z);
      l[seg + i * 4 + 3][orr] = tob(v.w);
    }
    __syncthreads();
#pragma unroll
    for (int i = 0; i < 2; ++i) {
      const int chunk = t + i * 256;
      const int row = chunk >> 3, sg = chunk & 7;
      *(bf16x8*)(dstT + (size_t)(c0 + row) * NC + o0 + sg * 8) = *(const bf16x8*)&l[row][sg * 8];
    }
  } else if (id < 768) {
    const int idx = id - 704;
#pragma unroll
    for (int i = 0; i < 4; ++i) {
      const int tt = idx * 1024 + i * 256 + t;
      float4 v = ((const float4*)wo)[tt];
      bf16x4 w;
      w[0] = tob(v.x); w[1] = tob(v.y); w[2] = tob(v.z); w[3] = tob(v.w);
      *(bf16x4*)(wob + (size_t)tt * 4) = w;
    }
  } else if (id < 776) {
    const int c0 = (id - 768) * 64;
    const int lane = t & 63, wave = t >> 6;
    const int c = c0 + lane;
    float s = 0.f;
    for (int o = wave * 128; o < wave * 128 + 128; ++o)
      s += wq[(size_t)(NC + o) * NC + c] * bqkv[o];
    float* red = (float*)smem;
    red[wave * 64 + lane] = s;
    __syncthreads();
    if (wave == 0) {
      float tot = red[lane] + red[64 + lane] + red[128 + lane] + red[192 + lane];
      rvec[c] = tot;
    }
  } else if (id < 784) {
    const int o = (id - 776) * 64 + (t >> 2);
    const int q = t & 3;
    const float4* wr = (const float4*)(wo + (size_t)o * NC + q * 128);
    const float4* bv = (const float4*)(bqkv + 2 * NC + q * 128);
    float s = 0.f;
#pragma unroll
    for (int i = 0; i < 32; ++i) {
      float4 w4 = wr[i], b4 = bv[i];
      s += (w4.x * b4.x + w4.y * b4.y) + (w4.z * b4.z + w4.w * b4.w);
    }
    s += __shfl_xor(s, 1);
    s += __shfl_xor(s, 2);
    if (q == 0) bc[o] = s;
  } else {
    float4* dst = (float4*)(rowsum + (id - 784) * 4096);
#pragma unroll
    for (int i = 0; i < 4; ++i) dst[i * 256 + t] = make_float4(0.f, 0.f, 0.f, 0.f);
  }
}

// ---------------------------------------------------------------------------
// K2: pack_x — xnT[b][n][c] = bf16(GN(x)) via 64c x 64n LDS-transpose tiles.
// grid 2048 (CPX=256 -> XCD=b/2), 8 blocks/CU: streaming at full parallelism
// (r7-proven structure).
// ---------------------------------------------------------------------------
__global__ void pack_x_kernel(const float* __restrict__ x,
                              const float* __restrict__ coefA,
                              const float* __restrict__ coefB,
                              __bf16* __restrict__ xnT) {
  const int L = xcd_swz(256);
  const int b = L >> 7, rem = L & 127;
  const int c0 = (rem >> 4) * 64, n0 = (rem & 15) * 64;
  __shared__ __bf16 l[64][72];  // [n][c]
  const int tid = threadIdx.x;
  const int cl = tid >> 2, seg = (tid & 3) * 16;
  const float ca = coefA[b * NC + c0 + cl], cb = coefB[b * NC + c0 + cl];
  const float4* src = (const float4*)(x + (size_t)(b * NC + c0 + cl) * NSPA + n0 + seg);
#pragma unroll
  for (int i = 0; i < 4; ++i) {
    float4 v = src[i];
    l[seg + i * 4 + 0][cl] = tob(v.x * ca + cb);
    l[seg + i * 4 + 1][cl] = tob(v.y * ca + cb);
    l[seg + i * 4 + 2][cl] = tob(v.z * ca + cb);
    l[seg + i * 4 + 3][cl] = tob(v.w * ca + cb);
  }
  __syncthreads();
#pragma unroll
  for (int i = 0; i < 2; ++i) {
    const int chunk = tid + i * 256;
    const int row = chunk >> 3, s = chunk & 7;
    *(bf16x8*)(xnT + (size_t)(b * NSPA + n0 + row) * NC + c0 + s * 8) =
        *(const bf16x8*)&l[row][s * 8];
  }
}

// ---------------------------------------------------------------------------
// r3 2-phase 128^2 BK=64 core (proven): XOR-swizzled LDS (0 conflicts),
// dbuf, setprio.
// ---------------------------------------------------------------------------
__device__ __forceinline__ void stage_pair(const __bf16* __restrict__ A, int lda,
                                           const __bf16* __restrict__ B, int ldb,
                                           int k0, __bf16* lAf, __bf16* lBf) {
  const int tid = threadIdx.x;
#pragma unroll
  for (int i = 0; i < 4; ++i) {
    const int idx = tid + i * 256;
    const int srow = idx >> 3;
    const int ss = ((idx & 7) ^ (srow & 7)) * 8;
    GLDS16(A + (size_t)srow * lda + k0 + ss, lAf + idx * 8);
    GLDS16(B + (size_t)srow * ldb + k0 + ss, lBf + idx * 8);
  }
}

__device__ __forceinline__ void gemm_core_db(const __bf16* __restrict__ A, int lda,
                                             const __bf16* __restrict__ B, int ldb,
                                             int K, __bf16 (*lA)[128][64],
                                             __bf16 (*lB)[128][64], f32x4 acc[4][4]) {
  const int tid = threadIdx.x;
  const int lane = tid & 63, wave = tid >> 6;
  const int wm = (wave >> 1) * 64, wn = (wave & 1) * 64;
  const int fr = lane & 15, fg = (lane >> 4) * 8;
  const int nt = K >> 6;

  stage_pair(A, lda, B, ldb, 0, &lA[0][0][0], &lB[0][0][0]);
  asm volatile("s_waitcnt vmcnt(0)" ::: "memory");
  __syncthreads();
  int cur = 0;
  for (int t = 0; t < nt; ++t) {
    if (t + 1 < nt)
      stage_pair(A, lda, B, ldb, (t + 1) * 64, &lA[cur ^ 1][0][0], &lB[cur ^ 1][0][0]);
    __builtin_amdgcn_s_setprio(1);
#pragma unroll
    for (int ks = 0; ks < 2; ++ks) {
      bf16x8 af[4], bfr[4];
#pragma unroll
      for (int mi = 0; mi < 4; ++mi) {
        const int r = wm + mi * 16 + fr;
        af[mi] = *(const bf16x8*)&lA[cur][r][(ks * 32 + fg) ^ ((r & 7) << 3)];
      }
#pragma unroll
      for (int ni = 0; ni < 4; ++ni) {
        const int r = wn + ni * 16 + fr;
        bfr[ni] = *(const bf16x8*)&lB[cur][r][(ks * 32 + fg) ^ ((r & 7) << 3)];
      }
#pragma unroll
      for (int mi = 0; mi < 4; ++mi)
#pragma unroll
        for (int ni = 0; ni < 4; ++ni)
          acc[mi][ni] = __builtin_amdgcn_mfma_f32_16x16x32_bf16(af[mi], bfr[ni], acc[mi][ni], 0, 0, 0);
    }
    __builtin_amdgcn_s_setprio(0);
    if (t + 1 < nt) {
      asm volatile("s_waitcnt vmcnt(0)" ::: "memory");
      __syncthreads();
      cur ^= 1;
    }
  }
}

// ===========================================================================
// K3: mid — one launch (grid 288): id<32 small GEMMs -> Aproj; id>=32 R.
// ===========================================================================
__global__ __launch_bounds__(256, 2) void mid_kernel(
    const __bf16* __restrict__ wqT, const __bf16* __restrict__ wkT,
    const __bf16* __restrict__ wvT, const __bf16* __restrict__ wob,
    const __bf16* __restrict__ xnT, const float* __restrict__ rvec,
    __bf16* __restrict__ Aproj, float* __restrict__ R) {
  __shared__ __bf16 lA[2][128][64], lB[2][128][64];
  const int id = blockIdx.x;
  if (id < 32) {
    const bool doM = id < 16;
    const int sub = doM ? id : id - 16;
    const int mt = sub >> 2, nt2 = sub & 3;
    const __bf16* A = doM ? (wqT + (size_t)mt * 128 * NC) : (wob + (size_t)mt * 128 * NC);
    const __bf16* B = doM ? (wkT + (size_t)nt2 * 128 * NC) : (wvT + (size_t)nt2 * 128 * NC);
    f32x4 acc[4][4] = {};
    gemm_core_db(A, NC, B, NC, NC, lA, lB, acc);

    const int tid = threadIdx.x;
    const int lane = tid & 63, wave = tid >> 6;
    const int wm = (wave >> 1) * 64, wn = (wave & 1) * 64;
    const int fr = lane & 15, fq4 = (lane >> 4) * 4;
    const int mbase = (doM ? 0 : NC) + mt * 128;
#pragma unroll
    for (int mi = 0; mi < 4; ++mi) {
      const int m = mbase + wm + mi * 16 + fq4;
#pragma unroll
      for (int ni = 0; ni < 4; ++ni) {
        const int n = nt2 * 128 + wn + ni * 16 + fr;
#pragma unroll
        for (int r = 0; r < 4; ++r)
          Aproj[(size_t)(m + r) * NC + n] = tob(acc[mi][ni][r]);
      }
    }
  } else {
    const int id2 = id - 32;
    const int L = (id2 & 7) * 32 + (id2 >> 3);  // CPX=32 -> XCD=b/2
    const int b = L >> 4, j0 = (L & 15) * 64;
    const int row = threadIdx.x >> 2, q = threadIdx.x & 3;
    const __bf16* src = xnT + ((size_t)(b * NSPA) + j0 + row) * NC + q * 128;
    const float* rv = rvec + q * 128;
    float s = 0.f;
#pragma unroll
    for (int i = 0; i < 16; ++i) {
      bf16x8 v = *(const bf16x8*)(src + i * 8);
#pragma unroll
      for (int e = 0; e < 8; ++e) s += (float)v[e] * rv[i * 8 + e];
    }
    s += __shfl_xor(s, 1);
    s += __shfl_xor(s, 2);
    if (q == 0) R[b * NSPA + j0 + row] = s;
  }
}

// ---------------------------------------------------------------------------
// K4: proj GEMM. C[m][n=(b,j)] = Aproj[m][:] . xn_j
//   m <  512: transposed store -> Yt[b][j][c]
//   m >= 512: natural store -> v'[b][d][j] + bc[d]
// grid 1024 (CPX=128 -> XCD=b/2)
// ---------------------------------------------------------------------------
__global__ __launch_bounds__(256, 2) void proj_kernel(
    const __bf16* __restrict__ Aproj, const __bf16* __restrict__ xnT,
    const float* __restrict__ bc, __bf16* __restrict__ Yt, __bf16* __restrict__ vp) {
  const int L = xcd_swz(128);
  const int pair = L >> 3, mblk = L & 7;
  const int b = pair >> 3;
  const int n0 = (pair & 7) * 128, m0 = mblk * 128;
  __shared__ __bf16 lA[2][128][64], lB[2][128][64];
  f32x4 acc[4][4] = {};
  gemm_core_db(Aproj + (size_t)m0 * NC, NC, xnT + ((size_t)b * NSPA + n0) * NC, NC,
               NC, lA, lB, acc);

  const int lane = threadIdx.x & 63, wave = threadIdx.x >> 6;
  const int wm = (wave >> 1) * 64, wn = (wave & 1) * 64;
  const int fr = lane & 15, fq4 = (lane >> 4) * 4;
  if (m0 < NC) {  // Y path: transposed store
#pragma unroll
    for (int mi = 0; mi < 4; ++mi) {
      const int m = m0 + wm + mi * 16 + fq4;
#pragma unroll
      for (int ni = 0; ni < 4; ++ni) {
        const int n = n0 + wn + ni * 16 + fr;
        bf16x4 w;
        w[0] = tob(acc[mi][ni][0]);
        w[1] = tob(acc[mi][ni][1]);
        w[2] = tob(acc[mi][ni][2]);
        w[3] = tob(acc[mi][ni][3]);
        *(bf16x4*)(Yt + ((size_t)b * NSPA + n) * NC + m) = w;
      }
    }
  } else {  // v' path: natural store + bc
#pragma unroll
    for (int mi = 0; mi < 4; ++mi) {
      const int m = m0 + wm + mi * 16 + fq4;
      const int d = m - NC;
      const float4 bias = *(const float4*)(bc + d);
#pragma unroll
      for (int ni = 0; ni < 4; ++ni) {
        const int n = n0 + wn + ni * 16 + fr;
        vp[((size_t)b * NC + d + 0) * NSPA + n] = tob(acc[mi][ni][0] + bias.x);
        vp[((size_t)b * NC + d + 1) * NSPA + n] = tob(acc[mi][ni][1] + bias.y);
        vp[((size_t)b * NC + d + 2) * NSPA + n] = tob(acc[mi][ni][2] + bias.z);
        vp[((size_t)b * NC + d + 3) * NSPA + n] = tob(acc[mi][ni][3] + bias.w);
      }
    }
  }
}

// ---------------------------------------------------------------------------
// K5: scores + exp + rowsum (softmax pass deleted; unnormalized exp).
// grid 1024 (CPX=128 -> XCD=b/2)
// ---------------------------------------------------------------------------
__global__ __launch_bounds__(256, 2) void scores_kernel(
    const __bf16* __restrict__ Yt, const __bf16* __restrict__ xnT,
    const float* __restrict__ R, __bf16* __restrict__ P,
    float* __restrict__ rowsum) {
  const int L = xcd_swz(128);
  const int b = L >> 6, r = L & 63;
  const int i0 = (r >> 3) * 128, j0 = (r & 7) * 128;
  __shared__ __bf16 lA[2][128][64], lB[2][128][64];
  f32x4 acc[4][4] = {};
  gemm_core_db(Yt + ((size_t)b * NSPA + j0) * NC, NC,
               xnT + ((size_t)b * NSPA + i0) * NC, NC, NC, lA, lB, acc);

  const int lane = threadIdx.x & 63, wave = threadIdx.x >> 6;
  const int wm = (wave >> 1) * 64, wn = (wave & 1) * 64;
  const int fr = lane & 15, fq4 = (lane >> 4) * 4;
  float rsum[4] = {0.f, 0.f, 0.f, 0.f};
#pragma unroll
  for (int mi = 0; mi < 4; ++mi) {
    const int j = j0 + wm + mi * 16 + fq4;
    const float4 Rb = *(const float4*)(R + b * NSPA + j);
#pragma unroll
    for (int ni = 0; ni < 4; ++ni) {
      const int i = i0 + wn + ni * 16 + fr;
      bf16x4 w;
      w[0] = tob(__expf((acc[mi][ni][0] + Rb.x) * SCL));
      w[1] = tob(__expf((acc[mi][ni][1] + Rb.y) * SCL));
      w[2] = tob(__expf((acc[mi][ni][2] + Rb.z) * SCL));
      w[3] = tob(__expf((acc[mi][ni][3] + Rb.w) * SCL));
      rsum[ni] += ((float)w[0] + (float)w[1]) + ((float)w[2] + (float)w[3]);
      *(bf16x4*)(P + ((size_t)b * NSPA + i) * NSPA + j) = w;
    }
  }
#pragma unroll
  for (int ni = 0; ni < 4; ++ni) {
    rsum[ni] += __shfl_xor(rsum[ni], 16);
    rsum[ni] += __shfl_xor(rsum[ni], 32);
  }
  if (lane < 16) {
#pragma unroll
    for (int ni = 0; ni < 4; ++ni)
      atomicAdd(&rowsum[b * NSPA + i0 + wn + ni * 16 + fr], rsum[ni]);
  }
}

// ---------------------------------------------------------------------------
// K6: PV + normalize + out fused. out = C/rowsum + bout + x (fp32).
// grid 512 (CPX=64 -> XCD=b/2)
// ---------------------------------------------------------------------------
__global__ __launch_bounds__(256, 2) void pvout_kernel(
    const __bf16* __restrict__ vp, const __bf16* __restrict__ P,
    const float* __restrict__ rowsum, const float* __restrict__ bout,
    const float* __restrict__ x, float* __restrict__ out) {
  const int L = xcd_swz(64);
  const int b = L >> 5, r = L & 31;
  const int d0 = (r >> 3) * 128, i0 = (r & 7) * 128;
  __shared__ __bf16 lA[2][128][64], lB[2][128][64];
  f32x4 acc[4][4] = {};
  gemm_core_db(vp + ((size_t)b * NC + d0) * NSPA, NSPA,
               P + ((size_t)b * NSPA + i0) * NSPA, NSPA, NSPA, lA, lB, acc);

  const int lane = threadIdx.x & 63, wave = threadIdx.x >> 6;
  const int wm = (wave >> 1) * 64, wn = (wave & 1) * 64;
  const int fr = lane & 15, fq4 = (lane >> 4) * 4;
  float inv[4];
#pragma unroll
  for (int ni = 0; ni < 4; ++ni)
    inv[ni] = 1.f / rowsum[b * NSPA + i0 + wn + ni * 16 + fr];
#pragma unroll
  for (int mi = 0; mi < 4; ++mi) {
    const int d = d0 + wm + mi * 16 + fq4;
    const float4 bias = *(const float4*)(bout + d);
#pragma unroll
    for (int ni = 0; ni < 4; ++ni) {
      const int i = i0 + wn + ni * 16 + fr;
      const size_t ix = ((size_t)b * NC + d) * NSPA + i;
      out[ix + 0 * NSPA] = acc[mi][ni][0] * inv[ni] + bias.x + x[ix + 0 * NSPA];
      out[ix + 1 * NSPA] = acc[mi][ni][1] * inv[ni] + bias.y + x[ix + 1 * NSPA];
      out[ix + 2 * NSPA] = acc[mi][ni][2] * inv[ni] + bias.z + x[ix + 2 * NSPA];
      out[ix + 3 * NSPA] = acc[mi][ni][3] * inv[ni] + bias.w + x[ix + 3 * NSPA];
    }
  }
}

// ---------------------------------------------------------------------------
// Workspace (~67 MB):
//   coefA/B 64KB | rvec/bc 4KB | R 64KB | rowsum 64KB | wqT/wkT/wvT/wob 2MB
//   Aproj 1MB | xnT 16MB | v' 16MB | P 32MB.  Yt (16MB) lives in d_out.
// ---------------------------------------------------------------------------
extern "C" void kernel_launch(void* const* d_in, const int* in_sizes, int n_in,
                              void* d_out, int out_size, void* d_ws, size_t ws_size,
                              hipStream_t stream) {
  const float* x        = (const float*)d_in[0];
  const float* gn_scale = (const float*)d_in[3];
  const float* gn_bias  = (const float*)d_in[4];
  const float* w_qkv    = (const float*)d_in[5];
  const float* b_qkv    = (const float*)d_in[6];
  const float* w_out    = (const float*)d_in[7];
  const float* b_out    = (const float*)d_in[8];
  float* out = (float*)d_out;

  float*  coefA  = (float*)d_ws;                 // 8192
  float*  coefB  = coefA + NB * NC;              // 8192
  float*  rvec   = coefB + NB * NC;              // 512
  float*  bc     = rvec + NC;                    // 512
  float*  R      = bc + NC;                      // 16384
  float*  rowsum = R + NB * NSPA;                // 16384
  __bf16* wqT    = (__bf16*)(rowsum + NB * NSPA);
  __bf16* wkT    = wqT + NC * NC;
  __bf16* wvT    = wkT + NC * NC;
  __bf16* wob    = wvT + NC * NC;
  __bf16* Aproj  = wob + NC * NC;                // 1024x512
  __bf16* xnT    = Aproj + 2 * NC * NC;          // 8M elems
  __bf16* vp     = xnT + (size_t)NB * NSPA * NC; // 8M elems
  __bf16* P      = vp + (size_t)NB * NC * NSPA;  // 16M elems
  __bf16* Yt     = (__bf16*)d_out;               // 16MB scratch in d_out

  stats_w_kernel<<<dim3(788), 256, 0, stream>>>(x, gn_scale, gn_bias, w_qkv, w_out,
                                                b_qkv, coefA, coefB, wqT, wkT, wvT,
                                                wob, rvec, bc, rowsum);
  pack_x_kernel<<<dim3(2048), 256, 0, stream>>>(x, coefA, coefB, xnT);
  mid_kernel<<<dim3(288), 256, 0, stream>>>(wqT, wkT, wvT, wob, xnT, rvec, Aproj, R);
  proj_kernel<<<dim3(1024), 256, 0, stream>>>(Aproj, xnT, bc, Yt, vp);
  scores_kernel<<<dim3(1024), 256, 0, stream>>>(Yt, xnT, R, P, rowsum);
  pvout_kernel<<<dim3(512), 256, 0, stream>>>(vp, P, rowsum, b_out, x, out);
}

// Round 14
// 120.207 us; speedup vs baseline: 1.1909x; 1.0330x over previous
//
#include <hip/hip_runtime.h>
#include <hip/hip_bf16.h>

// Shapes (fixed by the problem)
#define NB   16    // batch
#define NC   512   // channels
#define NSPA 1024  // h*w
#define GN_EPS 1e-5f
#define SCL 0.044194173824159216f  // 512^-0.5

typedef __bf16 bf16x8 __attribute__((ext_vector_type(8)));
typedef __bf16 bf16x4 __attribute__((ext_vector_type(4)));
typedef float  f32x4  __attribute__((ext_vector_type(4)));

typedef __attribute__((address_space(3))) void lds_t;
typedef const __attribute__((address_space(1))) void gl_t;
#define GLDS16(g, l) __builtin_amdgcn_global_load_lds((gl_t*)(g), (lds_t*)(l), 16, 0, 0)

__device__ __forceinline__ __bf16 tob(float f) { return (__bf16)f; }

// Bijective XCD-chunk swizzle (T1): each XCD gets a contiguous logical chunk.
__device__ __forceinline__ int xcd_swz(int cpx) {
  return (blockIdx.x & 7) * cpx + (blockIdx.x >> 3);
}

// ===========================================================================
// K1: stats_w — lightweight heterogeneous blocks (grid 788):
//   id <  512 : GN stats ONLY -> coefA/coefB
//   id <  704 : 64x64 transpose tiles wqT/wkT/wvT[c][o] bf16  (192 blocks)
//   id <  768 : pack Wout natural -> wob bf16                  (64 blocks)
//   id <  776 : rvec[c] = sum_o Wk[o][c]*bq[o]                 (8 blocks)
//   id <  784 : bc[o]   = sum_c Wout[o][c]*bv[c]               (8 blocks)
//   id <  788 : zero rowsum[16384] (re-zero every call)        (4 blocks)
// ===========================================================================
__global__ void stats_w_kernel(const float* __restrict__ x,
                               const float* __restrict__ gn_scale,
                               const float* __restrict__ gn_bias,
                               const float* __restrict__ wq,   // w_qkv [1536][512]
                               const float* __restrict__ wo,   // w_out [512][512]
                               const float* __restrict__ bqkv, // [1536]
                               float* __restrict__ coefA, float* __restrict__ coefB,
                               __bf16* __restrict__ wqT, __bf16* __restrict__ wkT,
                               __bf16* __restrict__ wvT, __bf16* __restrict__ wob,
                               float* __restrict__ rvec, float* __restrict__ bc,
                               float* __restrict__ rowsum) {
  __shared__ __align__(16) unsigned char smem[9216];
  const int id = blockIdx.x;
  const int t = threadIdx.x;
  if (id < 512) {
    const int L = (id & 7) * 64 + (id >> 3);   // XCD-chunk swizzle (CPX=64)
    const int b = L >> 5, g = L & 31;
    const float4* base = (const float4*)(x + (size_t)(b * NC + g * 16) * NSPA);
    float s = 0.f, ss = 0.f;
#pragma unroll
    for (int i = 0; i < 16; ++i) {
      float4 v = base[i * 256 + t];
      s  += (v.x + v.y) + (v.z + v.w);
      ss += (v.x * v.x + v.y * v.y) + (v.z * v.z + v.w * v.w);
    }
#pragma unroll
    for (int off = 32; off; off >>= 1) {
      s  += __shfl_xor(s, off);
      ss += __shfl_xor(ss, off);
    }
    float* red = (float*)smem;
    const int wave = t >> 6, lane = t & 63;
    if (lane == 0) { red[wave] = s; red[4 + wave] = ss; }
    __syncthreads();
    if (t < 16) {
      const float S  = red[0] + red[1] + red[2] + red[3];
      const float SS = red[4] + red[5] + red[6] + red[7];
      const float mean = S * (1.f / 16384.f);
      const float var  = SS * (1.f / 16384.f) - mean * mean;
      const float rstd = rsqrtf(var + GN_EPS);
      const int c = g * 16 + t;
      const float a = gn_scale[c] * rstd;
      coefA[b * NC + c] = a;
      coefB[b * NC + c] = gn_bias[c] - mean * a;
    }
  } else if (id < 704) {
    const int id2 = id - 512;
    const int mat = id2 >> 6, tile = id2 & 63;
    const int o0 = (tile >> 3) * 64, c0 = (tile & 7) * 64;
    __bf16* dstT = (mat == 0) ? wqT : (mat == 1) ? wkT : wvT;
    __bf16 (*l)[72] = (__bf16(*)[72])smem;
    const int orr = t >> 2, seg = (t & 3) * 16;
    const float4* src = (const float4*)(wq + (size_t)(mat * NC + o0 + orr) * NC + c0 + seg);
#pragma unroll
    for (int i = 0; i < 4; ++i) {
      float4 v = src[i];
      l[seg + i * 4 + 0][orr] = tob(v.x);
      l[seg + i * 4 + 1][orr] = tob(v.y);
      l[seg + i * 4 + 2][orr] = tob(v.z);
      l[seg + i * 4 + 3][orr] = tob(v.w);
    }
    __syncthreads();
#pragma unroll
    for (int i = 0; i < 2; ++i) {
      const int chunk = t + i * 256;
      const int row = chunk >> 3, sg = chunk & 7;
      *(bf16x8*)(dstT + (size_t)(c0 + row) * NC + o0 + sg * 8) = *(const bf16x8*)&l[row][sg * 8];
    }
  } else if (id < 768) {
    const int idx = id - 704;
#pragma unroll
    for (int i = 0; i < 4; ++i) {
      const int tt = idx * 1024 + i * 256 + t;
      float4 v = ((const float4*)wo)[tt];
      bf16x4 w;
      w[0] = tob(v.x); w[1] = tob(v.y); w[2] = tob(v.z); w[3] = tob(v.w);
      *(bf16x4*)(wob + (size_t)tt * 4) = w;
    }
  } else if (id < 776) {
    const int c0 = (id - 768) * 64;
    const int lane = t & 63, wave = t >> 6;
    const int c = c0 + lane;
    float s = 0.f;
    for (int o = wave * 128; o < wave * 128 + 128; ++o)
      s += wq[(size_t)(NC + o) * NC + c] * bqkv[o];
    float* red = (float*)smem;
    red[wave * 64 + lane] = s;
    __syncthreads();
    if (wave == 0) {
      float tot = red[lane] + red[64 + lane] + red[128 + lane] + red[192 + lane];
      rvec[c] = tot;
    }
  } else if (id < 784) {
    const int o = (id - 776) * 64 + (t >> 2);
    const int q = t & 3;
    const float4* wr = (const float4*)(wo + (size_t)o * NC + q * 128);
    const float4* bv = (const float4*)(bqkv + 2 * NC + q * 128);
    float s = 0.f;
#pragma unroll
    for (int i = 0; i < 32; ++i) {
      float4 w4 = wr[i], b4 = bv[i];
      s += (w4.x * b4.x + w4.y * b4.y) + (w4.z * b4.z + w4.w * b4.w);
    }
    s += __shfl_xor(s, 1);
    s += __shfl_xor(s, 2);
    if (q == 0) bc[o] = s;
  } else {
    float4* dst = (float4*)(rowsum + (id - 784) * 4096);
#pragma unroll
    for (int i = 0; i < 4; ++i) dst[i * 256 + t] = make_float4(0.f, 0.f, 0.f, 0.f);
  }
}

// ---------------------------------------------------------------------------
// K2: pack_x — xnT[b][n][c] = bf16(GN(x)) via 64c x 64n LDS-transpose tiles.
// grid 2048 (CPX=256 -> XCD=b/2), 8 blocks/CU.
// ---------------------------------------------------------------------------
__global__ void pack_x_kernel(const float* __restrict__ x,
                              const float* __restrict__ coefA,
                              const float* __restrict__ coefB,
                              __bf16* __restrict__ xnT) {
  const int L = xcd_swz(256);
  const int b = L >> 7, rem = L & 127;
  const int c0 = (rem >> 4) * 64, n0 = (rem & 15) * 64;
  __shared__ __bf16 l[64][72];  // [n][c]
  const int tid = threadIdx.x;
  const int cl = tid >> 2, seg = (tid & 3) * 16;
  const float ca = coefA[b * NC + c0 + cl], cb = coefB[b * NC + c0 + cl];
  const float4* src = (const float4*)(x + (size_t)(b * NC + c0 + cl) * NSPA + n0 + seg);
#pragma unroll
  for (int i = 0; i < 4; ++i) {
    float4 v = src[i];
    l[seg + i * 4 + 0][cl] = tob(v.x * ca + cb);
    l[seg + i * 4 + 1][cl] = tob(v.y * ca + cb);
    l[seg + i * 4 + 2][cl] = tob(v.z * ca + cb);
    l[seg + i * 4 + 3][cl] = tob(v.w * ca + cb);
  }
  __syncthreads();
#pragma unroll
  for (int i = 0; i < 2; ++i) {
    const int chunk = tid + i * 256;
    const int row = chunk >> 3, s = chunk & 7;
    *(bf16x8*)(xnT + (size_t)(b * NSPA + n0 + row) * NC + c0 + s * 8) =
        *(const bf16x8*)&l[row][s * 8];
  }
}

// ---------------------------------------------------------------------------
// SINGLE-BUFFERED m97-exact 128^2 BK=64 core: 32 KB LDS -> 4 blocks/CU.
// Per K-tile: stage -> __syncthreads() [HIP semantics drain vmcnt(0)] ->
// ds_read + 32 MFMA (setprio) -> __syncthreads().  The per-tile drain is
// hidden by CROSS-BLOCK overlap (m97/m114 mechanism: 874 TF with 3 blk/CU);
// our 0-conflict XOR swizzle retained (m97 even had 16-way conflicts).
// Barrier count per tile identical to the r3 dbuf core — only the
// prefetch-vs-occupancy tradeoff flips.
// ---------------------------------------------------------------------------
__device__ __forceinline__ void stage_pair(const __bf16* __restrict__ A, int lda,
                                           const __bf16* __restrict__ B, int ldb,
                                           int k0, __bf16* lAf, __bf16* lBf) {
  const int tid = threadIdx.x;
#pragma unroll
  for (int i = 0; i < 4; ++i) {
    const int idx = tid + i * 256;
    const int srow = idx >> 3;
    const int ss = ((idx & 7) ^ (srow & 7)) * 8;
    GLDS16(A + (size_t)srow * lda + k0 + ss, lAf + idx * 8);
    GLDS16(B + (size_t)srow * ldb + k0 + ss, lBf + idx * 8);
  }
}

__device__ __forceinline__ void gemm_core_sb(const __bf16* __restrict__ A, int lda,
                                             const __bf16* __restrict__ B, int ldb,
                                             int K, __bf16 (*lA)[64],
                                             __bf16 (*lB)[64], f32x4 acc[4][4]) {
  const int tid = threadIdx.x;
  const int lane = tid & 63, wave = tid >> 6;
  const int wm = (wave >> 1) * 64, wn = (wave & 1) * 64;
  const int fr = lane & 15, fg = (lane >> 4) * 8;
  const int nt = K >> 6;

  for (int t = 0; t < nt; ++t) {
    stage_pair(A, lda, B, ldb, t * 64, &lA[0][0], &lB[0][0]);
    __syncthreads();   // drains vmcnt(0)+lgkmcnt per HIP barrier semantics
    __builtin_amdgcn_s_setprio(1);
#pragma unroll
    for (int ks = 0; ks < 2; ++ks) {
      bf16x8 af[4], bfr[4];
#pragma unroll
      for (int mi = 0; mi < 4; ++mi) {
        const int r = wm + mi * 16 + fr;
        af[mi] = *(const bf16x8*)&lA[r][(ks * 32 + fg) ^ ((r & 7) << 3)];
      }
#pragma unroll
      for (int ni = 0; ni < 4; ++ni) {
        const int r = wn + ni * 16 + fr;
        bfr[ni] = *(const bf16x8*)&lB[r][(ks * 32 + fg) ^ ((r & 7) << 3)];
      }
#pragma unroll
      for (int mi = 0; mi < 4; ++mi)
#pragma unroll
        for (int ni = 0; ni < 4; ++ni)
          acc[mi][ni] = __builtin_amdgcn_mfma_f32_16x16x32_bf16(af[mi], bfr[ni], acc[mi][ni], 0, 0, 0);
    }
    __builtin_amdgcn_s_setprio(0);
    if (t + 1 < nt) __syncthreads();  // protect buffer before next stage
  }
}

// ===========================================================================
// K3: mid — one launch (grid 288): id<32 small GEMMs -> Aproj; id>=32 R.
// ===========================================================================
__global__ __launch_bounds__(256, 4) void mid_kernel(
    const __bf16* __restrict__ wqT, const __bf16* __restrict__ wkT,
    const __bf16* __restrict__ wvT, const __bf16* __restrict__ wob,
    const __bf16* __restrict__ xnT, const float* __restrict__ rvec,
    __bf16* __restrict__ Aproj, float* __restrict__ R) {
  __shared__ __bf16 lA[128][64], lB[128][64];
  const int id = blockIdx.x;
  if (id < 32) {
    const bool doM = id < 16;
    const int sub = doM ? id : id - 16;
    const int mt = sub >> 2, nt2 = sub & 3;
    const __bf16* A = doM ? (wqT + (size_t)mt * 128 * NC) : (wob + (size_t)mt * 128 * NC);
    const __bf16* B = doM ? (wkT + (size_t)nt2 * 128 * NC) : (wvT + (size_t)nt2 * 128 * NC);
    f32x4 acc[4][4] = {};
    gemm_core_sb(A, NC, B, NC, NC, lA, lB, acc);

    const int tid = threadIdx.x;
    const int lane = tid & 63, wave = tid >> 6;
    const int wm = (wave >> 1) * 64, wn = (wave & 1) * 64;
    const int fr = lane & 15, fq4 = (lane >> 4) * 4;
    const int mbase = (doM ? 0 : NC) + mt * 128;
#pragma unroll
    for (int mi = 0; mi < 4; ++mi) {
      const int m = mbase + wm + mi * 16 + fq4;
#pragma unroll
      for (int ni = 0; ni < 4; ++ni) {
        const int n = nt2 * 128 + wn + ni * 16 + fr;
#pragma unroll
        for (int r = 0; r < 4; ++r)
          Aproj[(size_t)(m + r) * NC + n] = tob(acc[mi][ni][r]);
      }
    }
  } else {
    const int id2 = id - 32;
    const int L = (id2 & 7) * 32 + (id2 >> 3);  // CPX=32 -> XCD=b/2
    const int b = L >> 4, j0 = (L & 15) * 64;
    const int row = threadIdx.x >> 2, q = threadIdx.x & 3;
    const __bf16* src = xnT + ((size_t)(b * NSPA) + j0 + row) * NC + q * 128;
    const float* rv = rvec + q * 128;
    float s = 0.f;
#pragma unroll
    for (int i = 0; i < 16; ++i) {
      bf16x8 v = *(const bf16x8*)(src + i * 8);
#pragma unroll
      for (int e = 0; e < 8; ++e) s += (float)v[e] * rv[i * 8 + e];
    }
    s += __shfl_xor(s, 1);
    s += __shfl_xor(s, 2);
    if (q == 0) R[b * NSPA + j0 + row] = s;
  }
}

// ---------------------------------------------------------------------------
// K4: proj GEMM. C[m][n=(b,j)] = Aproj[m][:] . xn_j
//   m <  512: transposed store -> Yt[b][j][c]
//   m >= 512: natural store -> v'[b][d][j] + bc[d]
// grid 1024 (CPX=128 -> XCD=b/2); 4 blocks/CU -> whole grid co-resident.
// ---------------------------------------------------------------------------
__global__ __launch_bounds__(256, 4) void proj_kernel(
    const __bf16* __restrict__ Aproj, const __bf16* __restrict__ xnT,
    const float* __restrict__ bc, __bf16* __restrict__ Yt, __bf16* __restrict__ vp) {
  const int L = xcd_swz(128);
  const int pair = L >> 3, mblk = L & 7;
  const int b = pair >> 3;
  const int n0 = (pair & 7) * 128, m0 = mblk * 128;
  __shared__ __bf16 lA[128][64], lB[128][64];
  f32x4 acc[4][4] = {};
  gemm_core_sb(Aproj + (size_t)m0 * NC, NC, xnT + ((size_t)b * NSPA + n0) * NC, NC,
               NC, lA, lB, acc);

  const int lane = threadIdx.x & 63, wave = threadIdx.x >> 6;
  const int wm = (wave >> 1) * 64, wn = (wave & 1) * 64;
  const int fr = lane & 15, fq4 = (lane >> 4) * 4;
  if (m0 < NC) {  // Y path: transposed store
#pragma unroll
    for (int mi = 0; mi < 4; ++mi) {
      const int m = m0 + wm + mi * 16 + fq4;
#pragma unroll
      for (int ni = 0; ni < 4; ++ni) {
        const int n = n0 + wn + ni * 16 + fr;
        bf16x4 w;
        w[0] = tob(acc[mi][ni][0]);
        w[1] = tob(acc[mi][ni][1]);
        w[2] = tob(acc[mi][ni][2]);
        w[3] = tob(acc[mi][ni][3]);
        *(bf16x4*)(Yt + ((size_t)b * NSPA + n) * NC + m) = w;
      }
    }
  } else {  // v' path: natural store + bc
#pragma unroll
    for (int mi = 0; mi < 4; ++mi) {
      const int m = m0 + wm + mi * 16 + fq4;
      const int d = m - NC;
      const float4 bias = *(const float4*)(bc + d);
#pragma unroll
      for (int ni = 0; ni < 4; ++ni) {
        const int n = n0 + wn + ni * 16 + fr;
        vp[((size_t)b * NC + d + 0) * NSPA + n] = tob(acc[mi][ni][0] + bias.x);
        vp[((size_t)b * NC + d + 1) * NSPA + n] = tob(acc[mi][ni][1] + bias.y);
        vp[((size_t)b * NC + d + 2) * NSPA + n] = tob(acc[mi][ni][2] + bias.z);
        vp[((size_t)b * NC + d + 3) * NSPA + n] = tob(acc[mi][ni][3] + bias.w);
      }
    }
  }
}

// ---------------------------------------------------------------------------
// K5: scores + exp + rowsum (unnormalized exp; softmax pass deleted).
// grid 1024 (CPX=128 -> XCD=b/2); 4 blocks/CU.
// ---------------------------------------------------------------------------
__global__ __launch_bounds__(256, 4) void scores_kernel(
    const __bf16* __restrict__ Yt, const __bf16* __restrict__ xnT,
    const float* __restrict__ R, __bf16* __restrict__ P,
    float* __restrict__ rowsum) {
  const int L = xcd_swz(128);
  const int b = L >> 6, r = L & 63;
  const int i0 = (r >> 3) * 128, j0 = (r & 7) * 128;
  __shared__ __bf16 lA[128][64], lB[128][64];
  f32x4 acc[4][4] = {};
  gemm_core_sb(Yt + ((size_t)b * NSPA + j0) * NC, NC,
               xnT + ((size_t)b * NSPA + i0) * NC, NC, NC, lA, lB, acc);

  const int lane = threadIdx.x & 63, wave = threadIdx.x >> 6;
  const int wm = (wave >> 1) * 64, wn = (wave & 1) * 64;
  const int fr = lane & 15, fq4 = (lane >> 4) * 4;
  float rsum[4] = {0.f, 0.f, 0.f, 0.f};
#pragma unroll
  for (int mi = 0; mi < 4; ++mi) {
    const int j = j0 + wm + mi * 16 + fq4;
    const float4 Rb = *(const float4*)(R + b * NSPA + j);
#pragma unroll
    for (int ni = 0; ni < 4; ++ni) {
      const int i = i0 + wn + ni * 16 + fr;
      bf16x4 w;
      w[0] = tob(__expf((acc[mi][ni][0] + Rb.x) * SCL));
      w[1] = tob(__expf((acc[mi][ni][1] + Rb.y) * SCL));
      w[2] = tob(__expf((acc[mi][ni][2] + Rb.z) * SCL));
      w[3] = tob(__expf((acc[mi][ni][3] + Rb.w) * SCL));
      rsum[ni] += ((float)w[0] + (float)w[1]) + ((float)w[2] + (float)w[3]);
      *(bf16x4*)(P + ((size_t)b * NSPA + i) * NSPA + j) = w;
    }
  }
#pragma unroll
  for (int ni = 0; ni < 4; ++ni) {
    rsum[ni] += __shfl_xor(rsum[ni], 16);
    rsum[ni] += __shfl_xor(rsum[ni], 32);
  }
  if (lane < 16) {
#pragma unroll
    for (int ni = 0; ni < 4; ++ni)
      atomicAdd(&rowsum[b * NSPA + i0 + wn + ni * 16 + fr], rsum[ni]);
  }
}

// ---------------------------------------------------------------------------
// K6: PV + normalize + out fused. out = C/rowsum + bout + x (fp32).
// grid 512 (CPX=64 -> XCD=b/2); 4 blocks/CU.
// ---------------------------------------------------------------------------
__global__ __launch_bounds__(256, 4) void pvout_kernel(
    const __bf16* __restrict__ vp, const __bf16* __restrict__ P,
    const float* __restrict__ rowsum, const float* __restrict__ bout,
    const float* __restrict__ x, float* __restrict__ out) {
  const int L = xcd_swz(64);
  const int b = L >> 5, r = L & 31;
  const int d0 = (r >> 3) * 128, i0 = (r & 7) * 128;
  __shared__ __bf16 lA[128][64], lB[128][64];
  f32x4 acc[4][4] = {};
  gemm_core_sb(vp + ((size_t)b * NC + d0) * NSPA, NSPA,
               P + ((size_t)b * NSPA + i0) * NSPA, NSPA, NSPA, lA, lB, acc);

  const int lane = threadIdx.x & 63, wave = threadIdx.x >> 6;
  const int wm = (wave >> 1) * 64, wn = (wave & 1) * 64;
  const int fr = lane & 15, fq4 = (lane >> 4) * 4;
  float inv[4];
#pragma unroll
  for (int ni = 0; ni < 4; ++ni)
    inv[ni] = 1.f / rowsum[b * NSPA + i0 + wn + ni * 16 + fr];
#pragma unroll
  for (int mi = 0; mi < 4; ++mi) {
    const int d = d0 + wm + mi * 16 + fq4;
    const float4 bias = *(const float4*)(bout + d);
#pragma unroll
    for (int ni = 0; ni < 4; ++ni) {
      const int i = i0 + wn + ni * 16 + fr;
      const size_t ix = ((size_t)b * NC + d) * NSPA + i;
      out[ix + 0 * NSPA] = acc[mi][ni][0] * inv[ni] + bias.x + x[ix + 0 * NSPA];
      out[ix + 1 * NSPA] = acc[mi][ni][1] * inv[ni] + bias.y + x[ix + 1 * NSPA];
      out[ix + 2 * NSPA] = acc[mi][ni][2] * inv[ni] + bias.z + x[ix + 2 * NSPA];
      out[ix + 3 * NSPA] = acc[mi][ni][3] * inv[ni] + bias.w + x[ix + 3 * NSPA];
    }
  }
}

// ---------------------------------------------------------------------------
// Workspace (~67 MB):
//   coefA/B 64KB | rvec/bc 4KB | R 64KB | rowsum 64KB | wqT/wkT/wvT/wob 2MB
//   Aproj 1MB | xnT 16MB | v' 16MB | P 32MB.  Yt (16MB) lives in d_out.
// ---------------------------------------------------------------------------
extern "C" void kernel_launch(void* const* d_in, const int* in_sizes, int n_in,
                              void* d_out, int out_size, void* d_ws, size_t ws_size,
                              hipStream_t stream) {
  const float* x        = (const float*)d_in[0];
  const float* gn_scale = (const float*)d_in[3];
  const float* gn_bias  = (const float*)d_in[4];
  const float* w_qkv    = (const float*)d_in[5];
  const float* b_qkv    = (const float*)d_in[6];
  const float* w_out    = (const float*)d_in[7];
  const float* b_out    = (const float*)d_in[8];
  float* out = (float*)d_out;

  float*  coefA  = (float*)d_ws;                 // 8192
  float*  coefB  = coefA + NB * NC;              // 8192
  float*  rvec   = coefB + NB * NC;              // 512
  float*  bc     = rvec + NC;                    // 512
  float*  R      = bc + NC;                      // 16384
  float*  rowsum = R + NB * NSPA;                // 16384
  __bf16* wqT    = (__bf16*)(rowsum + NB * NSPA);
  __bf16* wkT    = wqT + NC * NC;
  __bf16* wvT    = wkT + NC * NC;
  __bf16* wob    = wvT + NC * NC;
  __bf16* Aproj  = wob + NC * NC;                // 1024x512
  __bf16* xnT    = Aproj + 2 * NC * NC;          // 8M elems
  __bf16* vp     = xnT + (size_t)NB * NSPA * NC; // 8M elems
  __bf16* P      = vp + (size_t)NB * NC * NSPA;  // 16M elems
  __bf16* Yt     = (__bf16*)d_out;               // 16MB scratch in d_out

  stats_w_kernel<<<dim3(788), 256, 0, stream>>>(x, gn_scale, gn_bias, w_qkv, w_out,
                                                b_qkv, coefA, coefB, wqT, wkT, wvT,
                                                wob, rvec, bc, rowsum);
  pack_x_kernel<<<dim3(2048), 256, 0, stream>>>(x, coefA, coefB, xnT);
  mid_kernel<<<dim3(288), 256, 0, stream>>>(wqT, wkT, wvT, wob, xnT, rvec, Aproj, R);
  proj_kernel<<<dim3(1024), 256, 0, stream>>>(Aproj, xnT, bc, Yt, vp);
  scores_kernel<<<dim3(1024), 256, 0, stream>>>(Yt, xnT, R, P, rowsum);
  pvout_kernel<<<dim3(512), 256, 0, stream>>>(vp, P, rowsum, b_out, x, out);
}

// Round 15
// 119.830 us; speedup vs baseline: 1.1946x; 1.0032x over previous
//
#include <hip/hip_runtime.h>
#include <hip/hip_bf16.h>

// Shapes (fixed by the problem)
#define NB   16    // batch
#define NC   512   // channels
#define NSPA 1024  // h*w
#define GN_EPS 1e-5f
#define SCL 0.044194173824159216f  // 512^-0.5

typedef __bf16 bf16x8 __attribute__((ext_vector_type(8)));
typedef __bf16 bf16x4 __attribute__((ext_vector_type(4)));
typedef float  f32x4  __attribute__((ext_vector_type(4)));

typedef __attribute__((address_space(3))) void lds_t;
typedef const __attribute__((address_space(1))) void gl_t;
#define GLDS16(g, l) __builtin_amdgcn_global_load_lds((gl_t*)(g), (lds_t*)(l), 16, 0, 0)

__device__ __forceinline__ __bf16 tob(float f) { return (__bf16)f; }

// Bijective XCD-chunk swizzle (T1): each XCD gets a contiguous logical chunk.
__device__ __forceinline__ int xcd_swz(int cpx) {
  return (blockIdx.x & 7) * cpx + (blockIdx.x >> 3);
}

// ===========================================================================
// K1: stats_w — lightweight heterogeneous blocks (grid 788):
//   id <  512 : GN stats ONLY -> coefA/coefB
//   id <  704 : 64x64 transpose tiles wqT/wkT/wvT[c][o] bf16  (192 blocks)
//   id <  768 : pack Wout natural -> wob bf16                  (64 blocks)
//   id <  776 : rvec[c] = sum_o Wk[o][c]*bq[o]                 (8 blocks)
//   id <  784 : bc[o]   = sum_c Wout[o][c]*bv[c]               (8 blocks)
//   id <  788 : zero rowsum[16384] (re-zero every call)        (4 blocks)
// ===========================================================================
__global__ void stats_w_kernel(const float* __restrict__ x,
                               const float* __restrict__ gn_scale,
                               const float* __restrict__ gn_bias,
                               const float* __restrict__ wq,   // w_qkv [1536][512]
                               const float* __restrict__ wo,   // w_out [512][512]
                               const float* __restrict__ bqkv, // [1536]
                               float* __restrict__ coefA, float* __restrict__ coefB,
                               __bf16* __restrict__ wqT, __bf16* __restrict__ wkT,
                               __bf16* __restrict__ wvT, __bf16* __restrict__ wob,
                               float* __restrict__ rvec, float* __restrict__ bc,
                               float* __restrict__ rowsum) {
  __shared__ __align__(16) unsigned char smem[9216];
  const int id = blockIdx.x;
  const int t = threadIdx.x;
  if (id < 512) {
    const int L = (id & 7) * 64 + (id >> 3);   // XCD-chunk swizzle (CPX=64)
    const int b = L >> 5, g = L & 31;
    const float4* base = (const float4*)(x + (size_t)(b * NC + g * 16) * NSPA);
    float s = 0.f, ss = 0.f;
#pragma unroll
    for (int i = 0; i < 16; ++i) {
      float4 v = base[i * 256 + t];
      s  += (v.x + v.y) + (v.z + v.w);
      ss += (v.x * v.x + v.y * v.y) + (v.z * v.z + v.w * v.w);
    }
#pragma unroll
    for (int off = 32; off; off >>= 1) {
      s  += __shfl_xor(s, off);
      ss += __shfl_xor(ss, off);
    }
    float* red = (float*)smem;
    const int wave = t >> 6, lane = t & 63;
    if (lane == 0) { red[wave] = s; red[4 + wave] = ss; }
    __syncthreads();
    if (t < 16) {
      const float S  = red[0] + red[1] + red[2] + red[3];
      const float SS = red[4] + red[5] + red[6] + red[7];
      const float mean = S * (1.f / 16384.f);
      const float var  = SS * (1.f / 16384.f) - mean * mean;
      const float rstd = rsqrtf(var + GN_EPS);
      const int c = g * 16 + t;
      const float a = gn_scale[c] * rstd;
      coefA[b * NC + c] = a;
      coefB[b * NC + c] = gn_bias[c] - mean * a;
    }
  } else if (id < 704) {
    const int id2 = id - 512;
    const int mat = id2 >> 6, tile = id2 & 63;
    const int o0 = (tile >> 3) * 64, c0 = (tile & 7) * 64;
    __bf16* dstT = (mat == 0) ? wqT : (mat == 1) ? wkT : wvT;
    __bf16 (*l)[72] = (__bf16(*)[72])smem;
    const int orr = t >> 2, seg = (t & 3) * 16;
    const float4* src = (const float4*)(wq + (size_t)(mat * NC + o0 + orr) * NC + c0 + seg);
#pragma unroll
    for (int i = 0; i < 4; ++i) {
      float4 v = src[i];
      l[seg + i * 4 + 0][orr] = tob(v.x);
      l[seg + i * 4 + 1][orr] = tob(v.y);
      l[seg + i * 4 + 2][orr] = tob(v.z);
      l[seg + i * 4 + 3][orr] = tob(v.w);
    }
    __syncthreads();
#pragma unroll
    for (int i = 0; i < 2; ++i) {
      const int chunk = t + i * 256;
      const int row = chunk >> 3, sg = chunk & 7;
      *(bf16x8*)(dstT + (size_t)(c0 + row) * NC + o0 + sg * 8) = *(const bf16x8*)&l[row][sg * 8];
    }
  } else if (id < 768) {
    const int idx = id - 704;
#pragma unroll
    for (int i = 0; i < 4; ++i) {
      const int tt = idx * 1024 + i * 256 + t;
      float4 v = ((const float4*)wo)[tt];
      bf16x4 w;
      w[0] = tob(v.x); w[1] = tob(v.y); w[2] = tob(v.z); w[3] = tob(v.w);
      *(bf16x4*)(wob + (size_t)tt * 4) = w;
    }
  } else if (id < 776) {
    const int c0 = (id - 768) * 64;
    const int lane = t & 63, wave = t >> 6;
    const int c = c0 + lane;
    float s = 0.f;
    for (int o = wave * 128; o < wave * 128 + 128; ++o)
      s += wq[(size_t)(NC + o) * NC + c] * bqkv[o];
    float* red = (float*)smem;
    red[wave * 64 + lane] = s;
    __syncthreads();
    if (wave == 0) {
      float tot = red[lane] + red[64 + lane] + red[128 + lane] + red[192 + lane];
      rvec[c] = tot;
    }
  } else if (id < 784) {
    const int o = (id - 776) * 64 + (t >> 2);
    const int q = t & 3;
    const float4* wr = (const float4*)(wo + (size_t)o * NC + q * 128);
    const float4* bv = (const float4*)(bqkv + 2 * NC + q * 128);
    float s = 0.f;
#pragma unroll
    for (int i = 0; i < 32; ++i) {
      float4 w4 = wr[i], b4 = bv[i];
      s += (w4.x * b4.x + w4.y * b4.y) + (w4.z * b4.z + w4.w * b4.w);
    }
    s += __shfl_xor(s, 1);
    s += __shfl_xor(s, 2);
    if (q == 0) bc[o] = s;
  } else {
    float4* dst = (float4*)(rowsum + (id - 784) * 4096);
#pragma unroll
    for (int i = 0; i < 4; ++i) dst[i * 256 + t] = make_float4(0.f, 0.f, 0.f, 0.f);
  }
}

// ---------------------------------------------------------------------------
// K2: pack_x — xnT[b][n][c] = bf16(GN(x)) via 64c x 64n LDS-transpose tiles.
// grid 2048 (CPX=256 -> XCD=b/2), 8 blocks/CU.
// ---------------------------------------------------------------------------
__global__ void pack_x_kernel(const float* __restrict__ x,
                              const float* __restrict__ coefA,
                              const float* __restrict__ coefB,
                              __bf16* __restrict__ xnT) {
  const int L = xcd_swz(256);
  const int b = L >> 7, rem = L & 127;
  const int c0 = (rem >> 4) * 64, n0 = (rem & 15) * 64;
  __shared__ __bf16 l[64][72];  // [n][c]
  const int tid = threadIdx.x;
  const int cl = tid >> 2, seg = (tid & 3) * 16;
  const float ca = coefA[b * NC + c0 + cl], cb = coefB[b * NC + c0 + cl];
  const float4* src = (const float4*)(x + (size_t)(b * NC + c0 + cl) * NSPA + n0 + seg);
#pragma unroll
  for (int i = 0; i < 4; ++i) {
    float4 v = src[i];
    l[seg + i * 4 + 0][cl] = tob(v.x * ca + cb);
    l[seg + i * 4 + 1][cl] = tob(v.y * ca + cb);
    l[seg + i * 4 + 2][cl] = tob(v.z * ca + cb);
    l[seg + i * 4 + 3][cl] = tob(v.w * ca + cb);
  }
  __syncthreads();
#pragma unroll
  for (int i = 0; i < 2; ++i) {
    const int chunk = tid + i * 256;
    const int row = chunk >> 3, s = chunk & 7;
    *(bf16x8*)(xnT + (size_t)(b * NSPA + n0 + row) * NC + c0 + s * 8) =
        *(const bf16x8*)&l[row][s * 8];
  }
}

// ---------------------------------------------------------------------------
// SINGLE-BUFFERED m97-exact BK=64 core (r14-proven), templated on MROWS
// (A-tile rows: 128 or 64).  B-tile fixed 128 rows.  32/24.5 KB LDS ->
// 4 blocks/CU; per-tile vmcnt(0) drain hidden by cross-block overlap.
// 0-conflict XOR swizzle retained.
// ---------------------------------------------------------------------------
template <int MROWS>
__device__ __forceinline__ void stage_pair(const __bf16* __restrict__ A, int lda,
                                           const __bf16* __restrict__ B, int ldb,
                                           int k0, __bf16* lAf, __bf16* lBf) {
  const int tid = threadIdx.x;
#pragma unroll
  for (int i = 0; i < 4; ++i) {
    const int idx = tid + i * 256;
    const int srow = idx >> 3;
    const int ss = ((idx & 7) ^ (srow & 7)) * 8;
    GLDS16(B + (size_t)srow * ldb + k0 + ss, lBf + idx * 8);
  }
#pragma unroll
  for (int i = 0; i < MROWS / 32; ++i) {
    const int idx = tid + i * 256;
    const int srow = idx >> 3;
    const int ss = ((idx & 7) ^ (srow & 7)) * 8;
    GLDS16(A + (size_t)srow * lda + k0 + ss, lAf + idx * 8);
  }
}

template <int MROWS>
__device__ __forceinline__ void gemm_core_sb(const __bf16* __restrict__ A, int lda,
                                             const __bf16* __restrict__ B, int ldb,
                                             int K, __bf16 (*lA)[64],
                                             __bf16 (*lB)[64], f32x4 (*acc)[4]) {
  constexpr int MH = MROWS / 32;   // m-frags per wave
  const int tid = threadIdx.x;
  const int lane = tid & 63, wave = tid >> 6;
  const int wm = (wave >> 1) * (MROWS / 2), wn = (wave & 1) * 64;
  const int fr = lane & 15, fg = (lane >> 4) * 8;
  const int nt = K >> 6;

  for (int t = 0; t < nt; ++t) {
    stage_pair<MROWS>(A, lda, B, ldb, t * 64, &lA[0][0], &lB[0][0]);
    __syncthreads();   // drains vmcnt(0)+lgkmcnt per HIP barrier semantics
    __builtin_amdgcn_s_setprio(1);
#pragma unroll
    for (int ks = 0; ks < 2; ++ks) {
      bf16x8 af[MH], bfr[4];
#pragma unroll
      for (int mi = 0; mi < MH; ++mi) {
        const int r = wm + mi * 16 + fr;
        af[mi] = *(const bf16x8*)&lA[r][(ks * 32 + fg) ^ ((r & 7) << 3)];
      }
#pragma unroll
      for (int ni = 0; ni < 4; ++ni) {
        const int r = wn + ni * 16 + fr;
        bfr[ni] = *(const bf16x8*)&lB[r][(ks * 32 + fg) ^ ((r & 7) << 3)];
      }
#pragma unroll
      for (int mi = 0; mi < MH; ++mi)
#pragma unroll
        for (int ni = 0; ni < 4; ++ni)
          acc[mi][ni] = __builtin_amdgcn_mfma_f32_16x16x32_bf16(af[mi], bfr[ni], acc[mi][ni], 0, 0, 0);
    }
    __builtin_amdgcn_s_setprio(0);
    if (t + 1 < nt) __syncthreads();  // protect buffer before next stage
  }
}

// ===========================================================================
// K3: mid — one launch (grid 288): id<32 small GEMMs -> Aproj; id>=32 R.
// ===========================================================================
__global__ __launch_bounds__(256, 4) void mid_kernel(
    const __bf16* __restrict__ wqT, const __bf16* __restrict__ wkT,
    const __bf16* __restrict__ wvT, const __bf16* __restrict__ wob,
    const __bf16* __restrict__ xnT, const float* __restrict__ rvec,
    __bf16* __restrict__ Aproj, float* __restrict__ R) {
  __shared__ __bf16 lA[128][64], lB[128][64];
  const int id = blockIdx.x;
  if (id < 32) {
    const bool doM = id < 16;
    const int sub = doM ? id : id - 16;
    const int mt = sub >> 2, nt2 = sub & 3;
    const __bf16* A = doM ? (wqT + (size_t)mt * 128 * NC) : (wob + (size_t)mt * 128 * NC);
    const __bf16* B = doM ? (wkT + (size_t)nt2 * 128 * NC) : (wvT + (size_t)nt2 * 128 * NC);
    f32x4 acc[4][4] = {};
    gemm_core_sb<128>(A, NC, B, NC, NC, lA, lB, acc);

    const int tid = threadIdx.x;
    const int lane = tid & 63, wave = tid >> 6;
    const int wm = (wave >> 1) * 64, wn = (wave & 1) * 64;
    const int fr = lane & 15, fq4 = (lane >> 4) * 4;
    const int mbase = (doM ? 0 : NC) + mt * 128;
#pragma unroll
    for (int mi = 0; mi < 4; ++mi) {
      const int m = mbase + wm + mi * 16 + fq4;
#pragma unroll
      for (int ni = 0; ni < 4; ++ni) {
        const int n = nt2 * 128 + wn + ni * 16 + fr;
#pragma unroll
        for (int r = 0; r < 4; ++r)
          Aproj[(size_t)(m + r) * NC + n] = tob(acc[mi][ni][r]);
      }
    }
  } else {
    const int id2 = id - 32;
    const int L = (id2 & 7) * 32 + (id2 >> 3);  // CPX=32 -> XCD=b/2
    const int b = L >> 4, j0 = (L & 15) * 64;
    const int row = threadIdx.x >> 2, q = threadIdx.x & 3;
    const __bf16* src = xnT + ((size_t)(b * NSPA) + j0 + row) * NC + q * 128;
    const float* rv = rvec + q * 128;
    float s = 0.f;
#pragma unroll
    for (int i = 0; i < 16; ++i) {
      bf16x8 v = *(const bf16x8*)(src + i * 8);
#pragma unroll
      for (int e = 0; e < 8; ++e) s += (float)v[e] * rv[i * 8 + e];
    }
    s += __shfl_xor(s, 1);
    s += __shfl_xor(s, 2);
    if (q == 0) R[b * NSPA + j0 + row] = s;
  }
}

// ---------------------------------------------------------------------------
// K4: proj GEMM. C[m][n=(b,j)] = Aproj[m][:] . xn_j
//   m <  512: transposed store -> Yt[b][j][c]
//   m >= 512: natural store -> v'[b][d][j] + bc[d]
// grid 1024 (CPX=128 -> XCD=b/2); 4 blocks/CU -> whole grid co-resident.
// ---------------------------------------------------------------------------
__global__ __launch_bounds__(256, 4) void proj_kernel(
    const __bf16* __restrict__ Aproj, const __bf16* __restrict__ xnT,
    const float* __restrict__ bc, __bf16* __restrict__ Yt, __bf16* __restrict__ vp) {
  const int L = xcd_swz(128);
  const int pair = L >> 3, mblk = L & 7;
  const int b = pair >> 3;
  const int n0 = (pair & 7) * 128, m0 = mblk * 128;
  __shared__ __bf16 lA[128][64], lB[128][64];
  f32x4 acc[4][4] = {};
  gemm_core_sb<128>(Aproj + (size_t)m0 * NC, NC, xnT + ((size_t)b * NSPA + n0) * NC, NC,
                    NC, lA, lB, acc);

  const int lane = threadIdx.x & 63, wave = threadIdx.x >> 6;
  const int wm = (wave >> 1) * 64, wn = (wave & 1) * 64;
  const int fr = lane & 15, fq4 = (lane >> 4) * 4;
  if (m0 < NC) {  // Y path: transposed store
#pragma unroll
    for (int mi = 0; mi < 4; ++mi) {
      const int m = m0 + wm + mi * 16 + fq4;
#pragma unroll
      for (int ni = 0; ni < 4; ++ni) {
        const int n = n0 + wn + ni * 16 + fr;
        bf16x4 w;
        w[0] = tob(acc[mi][ni][0]);
        w[1] = tob(acc[mi][ni][1]);
        w[2] = tob(acc[mi][ni][2]);
        w[3] = tob(acc[mi][ni][3]);
        *(bf16x4*)(Yt + ((size_t)b * NSPA + n) * NC + m) = w;
      }
    }
  } else {  // v' path: natural store + bc
#pragma unroll
    for (int mi = 0; mi < 4; ++mi) {
      const int m = m0 + wm + mi * 16 + fq4;
      const int d = m - NC;
      const float4 bias = *(const float4*)(bc + d);
#pragma unroll
      for (int ni = 0; ni < 4; ++ni) {
        const int n = n0 + wn + ni * 16 + fr;
        vp[((size_t)b * NC + d + 0) * NSPA + n] = tob(acc[mi][ni][0] + bias.x);
        vp[((size_t)b * NC + d + 1) * NSPA + n] = tob(acc[mi][ni][1] + bias.y);
        vp[((size_t)b * NC + d + 2) * NSPA + n] = tob(acc[mi][ni][2] + bias.z);
        vp[((size_t)b * NC + d + 3) * NSPA + n] = tob(acc[mi][ni][3] + bias.w);
      }
    }
  }
}

// ---------------------------------------------------------------------------
// K5: scores + exp + rowsum (unnormalized exp; softmax pass deleted).
// grid 1024 (CPX=128 -> XCD=b/2); 4 blocks/CU.
// ---------------------------------------------------------------------------
__global__ __launch_bounds__(256, 4) void scores_kernel(
    const __bf16* __restrict__ Yt, const __bf16* __restrict__ xnT,
    const float* __restrict__ R, __bf16* __restrict__ P,
    float* __restrict__ rowsum) {
  const int L = xcd_swz(128);
  const int b = L >> 6, r = L & 63;
  const int i0 = (r >> 3) * 128, j0 = (r & 7) * 128;
  __shared__ __bf16 lA[128][64], lB[128][64];
  f32x4 acc[4][4] = {};
  gemm_core_sb<128>(Yt + ((size_t)b * NSPA + j0) * NC, NC,
                    xnT + ((size_t)b * NSPA + i0) * NC, NC, NC, lA, lB, acc);

  const int lane = threadIdx.x & 63, wave = threadIdx.x >> 6;
  const int wm = (wave >> 1) * 64, wn = (wave & 1) * 64;
  const int fr = lane & 15, fq4 = (lane >> 4) * 4;
  float rsum[4] = {0.f, 0.f, 0.f, 0.f};
#pragma unroll
  for (int mi = 0; mi < 4; ++mi) {
    const int j = j0 + wm + mi * 16 + fq4;
    const float4 Rb = *(const float4*)(R + b * NSPA + j);
#pragma unroll
    for (int ni = 0; ni < 4; ++ni) {
      const int i = i0 + wn + ni * 16 + fr;
      bf16x4 w;
      w[0] = tob(__expf((acc[mi][ni][0] + Rb.x) * SCL));
      w[1] = tob(__expf((acc[mi][ni][1] + Rb.y) * SCL));
      w[2] = tob(__expf((acc[mi][ni][2] + Rb.z) * SCL));
      w[3] = tob(__expf((acc[mi][ni][3] + Rb.w) * SCL));
      rsum[ni] += ((float)w[0] + (float)w[1]) + ((float)w[2] + (float)w[3]);
      *(bf16x4*)(P + ((size_t)b * NSPA + i) * NSPA + j) = w;
    }
  }
#pragma unroll
  for (int ni = 0; ni < 4; ++ni) {
    rsum[ni] += __shfl_xor(rsum[ni], 16);
    rsum[ni] += __shfl_xor(rsum[ni], 32);
  }
  if (lane < 16) {
#pragma unroll
    for (int ni = 0; ni < 4; ++ni)
      atomicAdd(&rowsum[b * NSPA + i0 + wn + ni * 16 + fr], rsum[ni]);
  }
}

// ---------------------------------------------------------------------------
// K6: PV + normalize + out fused, 64-row d-tiles (MROWS=64) -> grid 1024
// = 4 blocks/CU co-resident (was 512 = half-empty machine).
// C[d][i] = v'[d][:] . P[i][:] (K=1024); out = C/rowsum + bout + x (fp32).
// grid 1024 (CPX=128 -> XCD=b/2): b=L>>6, r=L&63, d0=(r>>3)*64, i0=(r&7)*128
// ---------------------------------------------------------------------------
__global__ __launch_bounds__(256, 4) void pvout_kernel(
    const __bf16* __restrict__ vp, const __bf16* __restrict__ P,
    const float* __restrict__ rowsum, const float* __restrict__ bout,
    const float* __restrict__ x, float* __restrict__ out) {
  const int L = xcd_swz(128);
  const int b = L >> 6, r = L & 63;
  const int d0 = (r >> 3) * 64, i0 = (r & 7) * 128;
  __shared__ __bf16 lA[64][64], lB[128][64];
  f32x4 acc[2][4] = {};
  gemm_core_sb<64>(vp + ((size_t)b * NC + d0) * NSPA, NSPA,
                   P + ((size_t)b * NSPA + i0) * NSPA, NSPA, NSPA, lA, lB, acc);

  const int lane = threadIdx.x & 63, wave = threadIdx.x >> 6;
  const int wm = (wave >> 1) * 32, wn = (wave & 1) * 64;
  const int fr = lane & 15, fq4 = (lane >> 4) * 4;
  float inv[4];
#pragma unroll
  for (int ni = 0; ni < 4; ++ni)
    inv[ni] = 1.f / rowsum[b * NSPA + i0 + wn + ni * 16 + fr];
#pragma unroll
  for (int mi = 0; mi < 2; ++mi) {
    const int d = d0 + wm + mi * 16 + fq4;
    const float4 bias = *(const float4*)(bout + d);
#pragma unroll
    for (int ni = 0; ni < 4; ++ni) {
      const int i = i0 + wn + ni * 16 + fr;
      const size_t ix = ((size_t)b * NC + d) * NSPA + i;
      out[ix + 0 * NSPA] = acc[mi][ni][0] * inv[ni] + bias.x + x[ix + 0 * NSPA];
      out[ix + 1 * NSPA] = acc[mi][ni][1] * inv[ni] + bias.y + x[ix + 1 * NSPA];
      out[ix + 2 * NSPA] = acc[mi][ni][2] * inv[ni] + bias.z + x[ix + 2 * NSPA];
      out[ix + 3 * NSPA] = acc[mi][ni][3] * inv[ni] + bias.w + x[ix + 3 * NSPA];
    }
  }
}

// ---------------------------------------------------------------------------
// Workspace (~67 MB):
//   coefA/B 64KB | rvec/bc 4KB | R 64KB | rowsum 64KB | wqT/wkT/wvT/wob 2MB
//   Aproj 1MB | xnT 16MB | v' 16MB | P 32MB.  Yt (16MB) lives in d_out.
// ---------------------------------------------------------------------------
extern "C" void kernel_launch(void* const* d_in, const int* in_sizes, int n_in,
                              void* d_out, int out_size, void* d_ws, size_t ws_size,
                              hipStream_t stream) {
  const float* x        = (const float*)d_in[0];
  const float* gn_scale = (const float*)d_in[3];
  const float* gn_bias  = (const float*)d_in[4];
  const float* w_qkv    = (const float*)d_in[5];
  const float* b_qkv    = (const float*)d_in[6];
  const float* w_out    = (const float*)d_in[7];
  const float* b_out    = (const float*)d_in[8];
  float* out = (float*)d_out;

  float*  coefA  = (float*)d_ws;                 // 8192
  float*  coefB  = coefA + NB * NC;              // 8192
  float*  rvec   = coefB + NB * NC;              // 512
  float*  bc     = rvec + NC;                    // 512
  float*  R      = bc + NC;                      // 16384
  float*  rowsum = R + NB * NSPA;                // 16384
  __bf16* wqT    = (__bf16*)(rowsum + NB * NSPA);
  __bf16* wkT    = wqT + NC * NC;
  __bf16* wvT    = wkT + NC * NC;
  __bf16* wob    = wvT + NC * NC;
  __bf16* Aproj  = wob + NC * NC;                // 1024x512
  __bf16* xnT    = Aproj + 2 * NC * NC;          // 8M elems
  __bf16* vp     = xnT + (size_t)NB * NSPA * NC; // 8M elems
  __bf16* P      = vp + (size_t)NB * NC * NSPA;  // 16M elems
  __bf16* Yt     = (__bf16*)d_out;               // 16MB scratch in d_out

  stats_w_kernel<<<dim3(788), 256, 0, stream>>>(x, gn_scale, gn_bias, w_qkv, w_out,
                                                b_qkv, coefA, coefB, wqT, wkT, wvT,
                                                wob, rvec, bc, rowsum);
  pack_x_kernel<<<dim3(2048), 256, 0, stream>>>(x, coefA, coefB, xnT);
  mid_kernel<<<dim3(288), 256, 0, stream>>>(wqT, wkT, wvT, wob, xnT, rvec, Aproj, R);
  proj_kernel<<<dim3(1024), 256, 0, stream>>>(Aproj, xnT, bc, Yt, vp);
  scores_kernel<<<dim3(1024), 256, 0, stream>>>(Yt, xnT, R, P, rowsum);
  pvout_kernel<<<dim3(1024), 256, 0, stream>>>(vp, P, rowsum, b_out, x, out);
}

// Round 16
// 117.316 us; speedup vs baseline: 1.2202x; 1.0214x over previous
//
#include <hip/hip_runtime.h>
#include <hip/hip_bf16.h>

// Shapes (fixed by the problem)
#define NB   16    // batch
#define NC   512   // channels
#define NSPA 1024  // h*w
#define GN_EPS 1e-5f
#define SCL 0.044194173824159216f  // 512^-0.5

typedef __bf16 bf16x8 __attribute__((ext_vector_type(8)));
typedef __bf16 bf16x4 __attribute__((ext_vector_type(4)));
typedef float  f32x4  __attribute__((ext_vector_type(4)));

typedef __attribute__((address_space(3))) void lds_t;
typedef const __attribute__((address_space(1))) void gl_t;
#define GLDS16(g, l) __builtin_amdgcn_global_load_lds((gl_t*)(g), (lds_t*)(l), 16, 0, 0)

__device__ __forceinline__ __bf16 tob(float f) { return (__bf16)f; }

// Bijective XCD-chunk swizzle (T1): each XCD gets a contiguous logical chunk.
__device__ __forceinline__ int xcd_swz(int cpx) {
  return (blockIdx.x & 7) * cpx + (blockIdx.x >> 3);
}

// ===========================================================================
// K1: stats_w — lightweight heterogeneous blocks (grid 792):
//   id <  512 : GN stats ONLY -> coefA/coefB
//   id <  704 : 64x64 transpose tiles wqT/wkT/wvT[c][o] bf16  (192 blocks)
//   id <  768 : pack Wout natural -> wob bf16                  (64 blocks)
//   id <  776 : rvec[c] = sum_o Wk[o][c]*bq[o]                 (8 blocks)
//   id <  784 : bc[o]   = sum_c Wout[o][c]*bv[c]               (8 blocks)
//   id <  792 : zero rowsum[16384] + R[16384] (every call)     (8 blocks)
// ===========================================================================
__global__ void stats_w_kernel(const float* __restrict__ x,
                               const float* __restrict__ gn_scale,
                               const float* __restrict__ gn_bias,
                               const float* __restrict__ wq,   // w_qkv [1536][512]
                               const float* __restrict__ wo,   // w_out [512][512]
                               const float* __restrict__ bqkv, // [1536]
                               float* __restrict__ coefA, float* __restrict__ coefB,
                               __bf16* __restrict__ wqT, __bf16* __restrict__ wkT,
                               __bf16* __restrict__ wvT, __bf16* __restrict__ wob,
                               float* __restrict__ rvec, float* __restrict__ bc,
                               float* __restrict__ rowsum, float* __restrict__ R) {
  __shared__ __align__(16) unsigned char smem[9216];
  const int id = blockIdx.x;
  const int t = threadIdx.x;
  if (id < 512) {
    const int L = (id & 7) * 64 + (id >> 3);   // XCD-chunk swizzle (CPX=64)
    const int b = L >> 5, g = L & 31;
    const float4* base = (const float4*)(x + (size_t)(b * NC + g * 16) * NSPA);
    float s = 0.f, ss = 0.f;
#pragma unroll
    for (int i = 0; i < 16; ++i) {
      float4 v = base[i * 256 + t];
      s  += (v.x + v.y) + (v.z + v.w);
      ss += (v.x * v.x + v.y * v.y) + (v.z * v.z + v.w * v.w);
    }
#pragma unroll
    for (int off = 32; off; off >>= 1) {
      s  += __shfl_xor(s, off);
      ss += __shfl_xor(ss, off);
    }
    float* red = (float*)smem;
    const int wave = t >> 6, lane = t & 63;
    if (lane == 0) { red[wave] = s; red[4 + wave] = ss; }
    __syncthreads();
    if (t < 16) {
      const float S  = red[0] + red[1] + red[2] + red[3];
      const float SS = red[4] + red[5] + red[6] + red[7];
      const float mean = S * (1.f / 16384.f);
      const float var  = SS * (1.f / 16384.f) - mean * mean;
      const float rstd = rsqrtf(var + GN_EPS);
      const int c = g * 16 + t;
      const float a = gn_scale[c] * rstd;
      coefA[b * NC + c] = a;
      coefB[b * NC + c] = gn_bias[c] - mean * a;
    }
  } else if (id < 704) {
    const int id2 = id - 512;
    const int mat = id2 >> 6, tile = id2 & 63;
    const int o0 = (tile >> 3) * 64, c0 = (tile & 7) * 64;
    __bf16* dstT = (mat == 0) ? wqT : (mat == 1) ? wkT : wvT;
    __bf16 (*l)[72] = (__bf16(*)[72])smem;
    const int orr = t >> 2, seg = (t & 3) * 16;
    const float4* src = (const float4*)(wq + (size_t)(mat * NC + o0 + orr) * NC + c0 + seg);
#pragma unroll
    for (int i = 0; i < 4; ++i) {
      float4 v = src[i];
      l[seg + i * 4 + 0][orr] = tob(v.x);
      l[seg + i * 4 + 1][orr] = tob(v.y);
      l[seg + i * 4 + 2][orr] = tob(v.z);
      l[seg + i * 4 + 3][orr] = tob(v.w);
    }
    __syncthreads();
#pragma unroll
    for (int i = 0; i < 2; ++i) {
      const int chunk = t + i * 256;
      const int row = chunk >> 3, sg = chunk & 7;
      *(bf16x8*)(dstT + (size_t)(c0 + row) * NC + o0 + sg * 8) = *(const bf16x8*)&l[row][sg * 8];
    }
  } else if (id < 768) {
    const int idx = id - 704;
#pragma unroll
    for (int i = 0; i < 4; ++i) {
      const int tt = idx * 1024 + i * 256 + t;
      float4 v = ((const float4*)wo)[tt];
      bf16x4 w;
      w[0] = tob(v.x); w[1] = tob(v.y); w[2] = tob(v.z); w[3] = tob(v.w);
      *(bf16x4*)(wob + (size_t)tt * 4) = w;
    }
  } else if (id < 776) {
    const int c0 = (id - 768) * 64;
    const int lane = t & 63, wave = t >> 6;
    const int c = c0 + lane;
    float s = 0.f;
    for (int o = wave * 128; o < wave * 128 + 128; ++o)
      s += wq[(size_t)(NC + o) * NC + c] * bqkv[o];
    float* red = (float*)smem;
    red[wave * 64 + lane] = s;
    __syncthreads();
    if (wave == 0) {
      float tot = red[lane] + red[64 + lane] + red[128 + lane] + red[192 + lane];
      rvec[c] = tot;
    }
  } else if (id < 784) {
    const int o = (id - 776) * 64 + (t >> 2);
    const int q = t & 3;
    const float4* wr = (const float4*)(wo + (size_t)o * NC + q * 128);
    const float4* bv = (const float4*)(bqkv + 2 * NC + q * 128);
    float s = 0.f;
#pragma unroll
    for (int i = 0; i < 32; ++i) {
      float4 w4 = wr[i], b4 = bv[i];
      s += (w4.x * b4.x + w4.y * b4.y) + (w4.z * b4.z + w4.w * b4.w);
    }
    s += __shfl_xor(s, 1);
    s += __shfl_xor(s, 2);
    if (q == 0) bc[o] = s;
  } else {
    // zero rowsum (4 blocks) then R (4 blocks) — ws is NOT re-poisoned
    // between timed replays, so both must be zeroed every call.
    const int z = id - 784;
    float* tgt = (z < 4) ? (rowsum + z * 4096) : (R + (z - 4) * 4096);
    float4* dst = (float4*)tgt;
#pragma unroll
    for (int i = 0; i < 4; ++i) dst[i * 256 + t] = make_float4(0.f, 0.f, 0.f, 0.f);
  }
}

// ---------------------------------------------------------------------------
// SINGLE-BUFFERED m97-exact BK=64 core (r14-proven), templated on MROWS.
// B-tile fixed 128 rows. 4 blocks/CU; per-tile vmcnt(0) drain hidden by
// cross-block overlap. 0-conflict XOR swizzle.
// ---------------------------------------------------------------------------
template <int MROWS>
__device__ __forceinline__ void stage_pair(const __bf16* __restrict__ A, int lda,
                                           const __bf16* __restrict__ B, int ldb,
                                           int k0, __bf16* lAf, __bf16* lBf) {
  const int tid = threadIdx.x;
#pragma unroll
  for (int i = 0; i < 4; ++i) {
    const int idx = tid + i * 256;
    const int srow = idx >> 3;
    const int ss = ((idx & 7) ^ (srow & 7)) * 8;
    GLDS16(B + (size_t)srow * ldb + k0 + ss, lBf + idx * 8);
  }
#pragma unroll
  for (int i = 0; i < MROWS / 32; ++i) {
    const int idx = tid + i * 256;
    const int srow = idx >> 3;
    const int ss = ((idx & 7) ^ (srow & 7)) * 8;
    GLDS16(A + (size_t)srow * lda + k0 + ss, lAf + idx * 8);
  }
}

template <int MROWS>
__device__ __forceinline__ void gemm_core_sb(const __bf16* __restrict__ A, int lda,
                                             const __bf16* __restrict__ B, int ldb,
                                             int K, __bf16 (*lA)[64],
                                             __bf16 (*lB)[64], f32x4 (*acc)[4]) {
  constexpr int MH = MROWS / 32;   // m-frags per wave
  const int tid = threadIdx.x;
  const int lane = tid & 63, wave = tid >> 6;
  const int wm = (wave >> 1) * (MROWS / 2), wn = (wave & 1) * 64;
  const int fr = lane & 15, fg = (lane >> 4) * 8;
  const int nt = K >> 6;

  for (int t = 0; t < nt; ++t) {
    stage_pair<MROWS>(A, lda, B, ldb, t * 64, &lA[0][0], &lB[0][0]);
    __syncthreads();   // drains vmcnt(0)+lgkmcnt per HIP barrier semantics
    __builtin_amdgcn_s_setprio(1);
#pragma unroll
    for (int ks = 0; ks < 2; ++ks) {
      bf16x8 af[MH], bfr[4];
#pragma unroll
      for (int mi = 0; mi < MH; ++mi) {
        const int r = wm + mi * 16 + fr;
        af[mi] = *(const bf16x8*)&lA[r][(ks * 32 + fg) ^ ((r & 7) << 3)];
      }
#pragma unroll
      for (int ni = 0; ni < 4; ++ni) {
        const int r = wn + ni * 16 + fr;
        bfr[ni] = *(const bf16x8*)&lB[r][(ks * 32 + fg) ^ ((r & 7) << 3)];
      }
#pragma unroll
      for (int mi = 0; mi < MH; ++mi)
#pragma unroll
        for (int ni = 0; ni < 4; ++ni)
          acc[mi][ni] = __builtin_amdgcn_mfma_f32_16x16x32_bf16(af[mi], bfr[ni], acc[mi][ni], 0, 0, 0);
    }
    __builtin_amdgcn_s_setprio(0);
    if (t + 1 < nt) __syncthreads();  // protect buffer before next stage
  }
}

// ===========================================================================
// K2: pack_mid — ONE launch replaces pack_x + mid (grid 2080):
//   id < 2048: pack blocks: xnT[b][n][c] = bf16(GN(x)) via 64x64 LDS
//              transpose; ALSO R[b][n] += rvec . xn partial (from the LDS
//              tile, quad-reduced, one atomicAdd per n) — R for free.
//   id >= 2048: 32 smallm GEMM blocks -> Aproj (id<16: M = Wq^T Wk;
//              else Wc = Wout Wv).  Independent of pack blocks.
// ===========================================================================
__global__ __launch_bounds__(256, 4) void pack_mid_kernel(
    const float* __restrict__ x, const float* __restrict__ coefA,
    const float* __restrict__ coefB, const float* __restrict__ rvec,
    const __bf16* __restrict__ wqT, const __bf16* __restrict__ wkT,
    const __bf16* __restrict__ wvT, const __bf16* __restrict__ wob,
    __bf16* __restrict__ xnT, float* __restrict__ R,
    __bf16* __restrict__ Aproj) {
  __shared__ __align__(16) __bf16 smem[2 * 128 * 64];  // 32 KB union
  const int id = blockIdx.x;
  const int tid = threadIdx.x;
  if (id < 2048) {
    const int L = (id & 7) * 256 + (id >> 3);  // XCD swizzle CPX=256 -> XCD=b/2
    const int b = L >> 7, rem = L & 127;
    const int c0 = (rem >> 4) * 64, n0 = (rem & 15) * 64;
    __bf16 (*l)[72] = (__bf16(*)[72])smem;     // [n][c], 9.2 KB of the union
    const int cl = tid >> 2, seg = (tid & 3) * 16;
    const float ca = coefA[b * NC + c0 + cl], cb = coefB[b * NC + c0 + cl];
    const float4* src = (const float4*)(x + (size_t)(b * NC + c0 + cl) * NSPA + n0 + seg);
#pragma unroll
    for (int i = 0; i < 4; ++i) {
      float4 v = src[i];
      l[seg + i * 4 + 0][cl] = tob(v.x * ca + cb);
      l[seg + i * 4 + 1][cl] = tob(v.y * ca + cb);
      l[seg + i * 4 + 2][cl] = tob(v.z * ca + cb);
      l[seg + i * 4 + 3][cl] = tob(v.w * ca + cb);
    }
    __syncthreads();
#pragma unroll
    for (int i = 0; i < 2; ++i) {
      const int chunk = tid + i * 256;
      const int row = chunk >> 3, s = chunk & 7;
      *(bf16x8*)(xnT + (size_t)(b * NSPA + n0 + row) * NC + c0 + s * 8) =
          *(const bf16x8*)&l[row][s * 8];
    }
    // R partial: n = tid>>2, q = tid&3 handles 16 c each; quad shfl-reduce.
    const int nn = tid >> 2, q = tid & 3;
    const float* rv = rvec + c0 + q * 16;
    float s = 0.f;
#pragma unroll
    for (int i = 0; i < 16; ++i) s += (float)l[nn][q * 16 + i] * rv[i];
    s += __shfl_xor(s, 1);
    s += __shfl_xor(s, 2);
    if (q == 0) atomicAdd(&R[b * NSPA + n0 + nn], s);
  } else {
    const int sub0 = id - 2048;
    const bool doM = sub0 < 16;
    const int sub = doM ? sub0 : sub0 - 16;
    const int mt = sub >> 2, nt2 = sub & 3;
    const __bf16* A = doM ? (wqT + (size_t)mt * 128 * NC) : (wob + (size_t)mt * 128 * NC);
    const __bf16* B = doM ? (wkT + (size_t)nt2 * 128 * NC) : (wvT + (size_t)nt2 * 128 * NC);
    __bf16 (*lA)[64] = (__bf16(*)[64])smem;
    __bf16 (*lB)[64] = (__bf16(*)[64])(smem + 128 * 64);
    f32x4 acc[4][4] = {};
    gemm_core_sb<128>(A, NC, B, NC, NC, lA, lB, acc);

    const int lane = tid & 63, wave = tid >> 6;
    const int wm = (wave >> 1) * 64, wn = (wave & 1) * 64;
    const int fr = lane & 15, fq4 = (lane >> 4) * 4;
    const int mbase = (doM ? 0 : NC) + mt * 128;
#pragma unroll
    for (int mi = 0; mi < 4; ++mi) {
      const int m = mbase + wm + mi * 16 + fq4;
#pragma unroll
      for (int ni = 0; ni < 4; ++ni) {
        const int n = nt2 * 128 + wn + ni * 16 + fr;
#pragma unroll
        for (int r = 0; r < 4; ++r)
          Aproj[(size_t)(m + r) * NC + n] = tob(acc[mi][ni][r]);
      }
    }
  }
}

// ---------------------------------------------------------------------------
// K3: proj GEMM. C[m][n=(b,j)] = Aproj[m][:] . xn_j
//   m <  512: transposed store -> Yt[b][j][c]
//   m >= 512: natural store -> v'[b][d][j] + bc[d]
// grid 1024 (CPX=128 -> XCD=b/2); 4 blocks/CU -> whole grid co-resident.
// ---------------------------------------------------------------------------
__global__ __launch_bounds__(256, 4) void proj_kernel(
    const __bf16* __restrict__ Aproj, const __bf16* __restrict__ xnT,
    const float* __restrict__ bc, __bf16* __restrict__ Yt, __bf16* __restrict__ vp) {
  const int L = xcd_swz(128);
  const int pair = L >> 3, mblk = L & 7;
  const int b = pair >> 3;
  const int n0 = (pair & 7) * 128, m0 = mblk * 128;
  __shared__ __bf16 lA[128][64], lB[128][64];
  f32x4 acc[4][4] = {};
  gemm_core_sb<128>(Aproj + (size_t)m0 * NC, NC, xnT + ((size_t)b * NSPA + n0) * NC, NC,
                    NC, lA, lB, acc);

  const int lane = threadIdx.x & 63, wave = threadIdx.x >> 6;
  const int wm = (wave >> 1) * 64, wn = (wave & 1) * 64;
  const int fr = lane & 15, fq4 = (lane >> 4) * 4;
  if (m0 < NC) {  // Y path: transposed store
#pragma unroll
    for (int mi = 0; mi < 4; ++mi) {
      const int m = m0 + wm + mi * 16 + fq4;
#pragma unroll
      for (int ni = 0; ni < 4; ++ni) {
        const int n = n0 + wn + ni * 16 + fr;
        bf16x4 w;
        w[0] = tob(acc[mi][ni][0]);
        w[1] = tob(acc[mi][ni][1]);
        w[2] = tob(acc[mi][ni][2]);
        w[3] = tob(acc[mi][ni][3]);
        *(bf16x4*)(Yt + ((size_t)b * NSPA + n) * NC + m) = w;
      }
    }
  } else {  // v' path: natural store + bc
#pragma unroll
    for (int mi = 0; mi < 4; ++mi) {
      const int m = m0 + wm + mi * 16 + fq4;
      const int d = m - NC;
      const float4 bias = *(const float4*)(bc + d);
#pragma unroll
      for (int ni = 0; ni < 4; ++ni) {
        const int n = n0 + wn + ni * 16 + fr;
        vp[((size_t)b * NC + d + 0) * NSPA + n] = tob(acc[mi][ni][0] + bias.x);
        vp[((size_t)b * NC + d + 1) * NSPA + n] = tob(acc[mi][ni][1] + bias.y);
        vp[((size_t)b * NC + d + 2) * NSPA + n] = tob(acc[mi][ni][2] + bias.z);
        vp[((size_t)b * NC + d + 3) * NSPA + n] = tob(acc[mi][ni][3] + bias.w);
      }
    }
  }
}

// ---------------------------------------------------------------------------
// K4: scores + exp + rowsum (unnormalized exp; softmax pass deleted).
// grid 1024 (CPX=128 -> XCD=b/2); 4 blocks/CU.
// ---------------------------------------------------------------------------
__global__ __launch_bounds__(256, 4) void scores_kernel(
    const __bf16* __restrict__ Yt, const __bf16* __restrict__ xnT,
    const float* __restrict__ R, __bf16* __restrict__ P,
    float* __restrict__ rowsum) {
  const int L = xcd_swz(128);
  const int b = L >> 6, r = L & 63;
  const int i0 = (r >> 3) * 128, j0 = (r & 7) * 128;
  __shared__ __bf16 lA[128][64], lB[128][64];
  f32x4 acc[4][4] = {};
  gemm_core_sb<128>(Yt + ((size_t)b * NSPA + j0) * NC, NC,
                    xnT + ((size_t)b * NSPA + i0) * NC, NC, NC, lA, lB, acc);

  const int lane = threadIdx.x & 63, wave = threadIdx.x >> 6;
  const int wm = (wave >> 1) * 64, wn = (wave & 1) * 64;
  const int fr = lane & 15, fq4 = (lane >> 4) * 4;
  float rsum[4] = {0.f, 0.f, 0.f, 0.f};
#pragma unroll
  for (int mi = 0; mi < 4; ++mi) {
    const int j = j0 + wm + mi * 16 + fq4;
    const float4 Rb = *(const float4*)(R + b * NSPA + j);
#pragma unroll
    for (int ni = 0; ni < 4; ++ni) {
      const int i = i0 + wn + ni * 16 + fr;
      bf16x4 w;
      w[0] = tob(__expf((acc[mi][ni][0] + Rb.x) * SCL));
      w[1] = tob(__expf((acc[mi][ni][1] + Rb.y) * SCL));
      w[2] = tob(__expf((acc[mi][ni][2] + Rb.z) * SCL));
      w[3] = tob(__expf((acc[mi][ni][3] + Rb.w) * SCL));
      rsum[ni] += ((float)w[0] + (float)w[1]) + ((float)w[2] + (float)w[3]);
      *(bf16x4*)(P + ((size_t)b * NSPA + i) * NSPA + j) = w;
    }
  }
#pragma unroll
  for (int ni = 0; ni < 4; ++ni) {
    rsum[ni] += __shfl_xor(rsum[ni], 16);
    rsum[ni] += __shfl_xor(rsum[ni], 32);
  }
  if (lane < 16) {
#pragma unroll
    for (int ni = 0; ni < 4; ++ni)
      atomicAdd(&rowsum[b * NSPA + i0 + wn + ni * 16 + fr], rsum[ni]);
  }
}

// ---------------------------------------------------------------------------
// K5: PV + normalize + out fused, 64-row d-tiles -> grid 1024 co-resident.
// C[d][i] = v'[d][:] . P[i][:] (K=1024); out = C/rowsum + bout + x (fp32).
// grid 1024 (CPX=128 -> XCD=b/2)
// ---------------------------------------------------------------------------
__global__ __launch_bounds__(256, 4) void pvout_kernel(
    const __bf16* __restrict__ vp, const __bf16* __restrict__ P,
    const float* __restrict__ rowsum, const float* __restrict__ bout,
    const float* __restrict__ x, float* __restrict__ out) {
  const int L = xcd_swz(128);
  const int b = L >> 6, r = L & 63;
  const int d0 = (r >> 3) * 64, i0 = (r & 7) * 128;
  __shared__ __bf16 lA[64][64], lB[128][64];
  f32x4 acc[2][4] = {};
  gemm_core_sb<64>(vp + ((size_t)b * NC + d0) * NSPA, NSPA,
                   P + ((size_t)b * NSPA + i0) * NSPA, NSPA, NSPA, lA, lB, acc);

  const int lane = threadIdx.x & 63, wave = threadIdx.x >> 6;
  const int wm = (wave >> 1) * 32, wn = (wave & 1) * 64;
  const int fr = lane & 15, fq4 = (lane >> 4) * 4;
  float inv[4];
#pragma unroll
  for (int ni = 0; ni < 4; ++ni)
    inv[ni] = 1.f / rowsum[b * NSPA + i0 + wn + ni * 16 + fr];
#pragma unroll
  for (int mi = 0; mi < 2; ++mi) {
    const int d = d0 + wm + mi * 16 + fq4;
    const float4 bias = *(const float4*)(bout + d);
#pragma unroll
    for (int ni = 0; ni < 4; ++ni) {
      const int i = i0 + wn + ni * 16 + fr;
      const size_t ix = ((size_t)b * NC + d) * NSPA + i;
      out[ix + 0 * NSPA] = acc[mi][ni][0] * inv[ni] + bias.x + x[ix + 0 * NSPA];
      out[ix + 1 * NSPA] = acc[mi][ni][1] * inv[ni] + bias.y + x[ix + 1 * NSPA];
      out[ix + 2 * NSPA] = acc[mi][ni][2] * inv[ni] + bias.z + x[ix + 2 * NSPA];
      out[ix + 3 * NSPA] = acc[mi][ni][3] * inv[ni] + bias.w + x[ix + 3 * NSPA];
    }
  }
}

// ---------------------------------------------------------------------------
// Workspace (~67 MB):
//   coefA/B 64KB | rvec/bc 4KB | R 64KB | rowsum 64KB | wqT/wkT/wvT/wob 2MB
//   Aproj 1MB | xnT 16MB | v' 16MB | P 32MB.  Yt (16MB) lives in d_out.
// ---------------------------------------------------------------------------
extern "C" void kernel_launch(void* const* d_in, const int* in_sizes, int n_in,
                              void* d_out, int out_size, void* d_ws, size_t ws_size,
                              hipStream_t stream) {
  const float* x        = (const float*)d_in[0];
  const float* gn_scale = (const float*)d_in[3];
  const float* gn_bias  = (const float*)d_in[4];
  const float* w_qkv    = (const float*)d_in[5];
  const float* b_qkv    = (const float*)d_in[6];
  const float* w_out    = (const float*)d_in[7];
  const float* b_out    = (const float*)d_in[8];
  float* out = (float*)d_out;

  float*  coefA  = (float*)d_ws;                 // 8192
  float*  coefB  = coefA + NB * NC;              // 8192
  float*  rvec   = coefB + NB * NC;              // 512
  float*  bc     = rvec + NC;                    // 512
  float*  R      = bc + NC;                      // 16384
  float*  rowsum = R + NB * NSPA;                // 16384
  __bf16* wqT    = (__bf16*)(rowsum + NB * NSPA);
  __bf16* wkT    = wqT + NC * NC;
  __bf16* wvT    = wkT + NC * NC;
  __bf16* wob    = wvT + NC * NC;
  __bf16* Aproj  = wob + NC * NC;                // 1024x512
  __bf16* xnT    = Aproj + 2 * NC * NC;          // 8M elems
  __bf16* vp     = xnT + (size_t)NB * NSPA * NC; // 8M elems
  __bf16* P      = vp + (size_t)NB * NC * NSPA;  // 16M elems
  __bf16* Yt     = (__bf16*)d_out;               // 16MB scratch in d_out

  stats_w_kernel<<<dim3(792), 256, 0, stream>>>(x, gn_scale, gn_bias, w_qkv, w_out,
                                                b_qkv, coefA, coefB, wqT, wkT, wvT,
                                                wob, rvec, bc, rowsum, R);
  pack_mid_kernel<<<dim3(2080), 256, 0, stream>>>(x, coefA, coefB, rvec, wqT, wkT,
                                                  wvT, wob, xnT, R, Aproj);
  proj_kernel<<<dim3(1024), 256, 0, stream>>>(Aproj, xnT, bc, Yt, vp);
  scores_kernel<<<dim3(1024), 256, 0, stream>>>(Yt, xnT, R, P, rowsum);
  pvout_kernel<<<dim3(1024), 256, 0, stream>>>(vp, P, rowsum, b_out, x, out);
}

// Round 17
// 110.530 us; speedup vs baseline: 1.2951x; 1.0614x over previous
//
#include <hip/hip_runtime.h>
#include <hip/hip_bf16.h>

// Shapes (fixed by the problem)
#define NB   16    // batch
#define NC   512   // channels
#define NSPA 1024  // h*w
#define GN_EPS 1e-5f
#define SCL 0.044194173824159216f  // 512^-0.5

typedef __bf16 bf16x8 __attribute__((ext_vector_type(8)));
typedef __bf16 bf16x4 __attribute__((ext_vector_type(4)));
typedef float  f32x4  __attribute__((ext_vector_type(4)));

typedef __attribute__((address_space(3))) void lds_t;
typedef const __attribute__((address_space(1))) void gl_t;
#define GLDS16(g, l) __builtin_amdgcn_global_load_lds((gl_t*)(g), (lds_t*)(l), 16, 0, 0)

__device__ __forceinline__ __bf16 tob(float f) { return (__bf16)f; }

// Bijective XCD-chunk swizzle (T1): each XCD gets a contiguous logical chunk.
__device__ __forceinline__ int xcd_swz(int cpx) {
  return (blockIdx.x & 7) * cpx + (blockIdx.x >> 3);
}

// ===========================================================================
// K1: stats_w — lightweight heterogeneous blocks (grid 792):
//   id <  512 : GN stats ONLY -> coefA/coefB
//   id <  704 : 64x64 transpose tiles wqT/wkT/wvT[c][o] bf16  (192 blocks)
//   id <  768 : pack Wout natural -> wob bf16                  (64 blocks)
//   id <  776 : rvec[c] = sum_o Wk[o][c]*bq[o]  (8-way ILP — the old
//               non-unrolled 128-iter serial-latency loop was ~40 us with
//               the GPU idle; THE hidden long pole since r9)
//   id <  784 : bc[o]   = sum_c Wout[o][c]*bv[c]               (8 blocks)
//   id <  792 : zero rowsum[16384] + R[16384] (every call)     (8 blocks)
// ===========================================================================
__global__ void stats_w_kernel(const float* __restrict__ x,
                               const float* __restrict__ gn_scale,
                               const float* __restrict__ gn_bias,
                               const float* __restrict__ wq,   // w_qkv [1536][512]
                               const float* __restrict__ wo,   // w_out [512][512]
                               const float* __restrict__ bqkv, // [1536]
                               float* __restrict__ coefA, float* __restrict__ coefB,
                               __bf16* __restrict__ wqT, __bf16* __restrict__ wkT,
                               __bf16* __restrict__ wvT, __bf16* __restrict__ wob,
                               float* __restrict__ rvec, float* __restrict__ bc,
                               float* __restrict__ rowsum, float* __restrict__ R) {
  __shared__ __align__(16) unsigned char smem[9216];
  const int id = blockIdx.x;
  const int t = threadIdx.x;
  if (id < 512) {
    const int L = (id & 7) * 64 + (id >> 3);   // XCD-chunk swizzle (CPX=64)
    const int b = L >> 5, g = L & 31;
    const float4* base = (const float4*)(x + (size_t)(b * NC + g * 16) * NSPA);
    float s = 0.f, ss = 0.f;
#pragma unroll
    for (int i = 0; i < 16; ++i) {
      float4 v = base[i * 256 + t];
      s  += (v.x + v.y) + (v.z + v.w);
      ss += (v.x * v.x + v.y * v.y) + (v.z * v.z + v.w * v.w);
    }
#pragma unroll
    for (int off = 32; off; off >>= 1) {
      s  += __shfl_xor(s, off);
      ss += __shfl_xor(ss, off);
    }
    float* red = (float*)smem;
    const int wave = t >> 6, lane = t & 63;
    if (lane == 0) { red[wave] = s; red[4 + wave] = ss; }
    __syncthreads();
    if (t < 16) {
      const float S  = red[0] + red[1] + red[2] + red[3];
      const float SS = red[4] + red[5] + red[6] + red[7];
      const float mean = S * (1.f / 16384.f);
      const float var  = SS * (1.f / 16384.f) - mean * mean;
      const float rstd = rsqrtf(var + GN_EPS);
      const int c = g * 16 + t;
      const float a = gn_scale[c] * rstd;
      coefA[b * NC + c] = a;
      coefB[b * NC + c] = gn_bias[c] - mean * a;
    }
  } else if (id < 704) {
    const int id2 = id - 512;
    const int mat = id2 >> 6, tile = id2 & 63;
    const int o0 = (tile >> 3) * 64, c0 = (tile & 7) * 64;
    __bf16* dstT = (mat == 0) ? wqT : (mat == 1) ? wkT : wvT;
    __bf16 (*l)[72] = (__bf16(*)[72])smem;
    const int orr = t >> 2, seg = (t & 3) * 16;
    const float4* src = (const float4*)(wq + (size_t)(mat * NC + o0 + orr) * NC + c0 + seg);
#pragma unroll
    for (int i = 0; i < 4; ++i) {
      float4 v = src[i];
      l[seg + i * 4 + 0][orr] = tob(v.x);
      l[seg + i * 4 + 1][orr] = tob(v.y);
      l[seg + i * 4 + 2][orr] = tob(v.z);
      l[seg + i * 4 + 3][orr] = tob(v.w);
    }
    __syncthreads();
#pragma unroll
    for (int i = 0; i < 2; ++i) {
      const int chunk = t + i * 256;
      const int row = chunk >> 3, sg = chunk & 7;
      *(bf16x8*)(dstT + (size_t)(c0 + row) * NC + o0 + sg * 8) = *(const bf16x8*)&l[row][sg * 8];
    }
  } else if (id < 768) {
    const int idx = id - 704;
#pragma unroll
    for (int i = 0; i < 4; ++i) {
      const int tt = idx * 1024 + i * 256 + t;
      float4 v = ((const float4*)wo)[tt];
      bf16x4 w;
      w[0] = tob(v.x); w[1] = tob(v.y); w[2] = tob(v.z); w[3] = tob(v.w);
      *(bf16x4*)(wob + (size_t)tt * 4) = w;
    }
  } else if (id < 776) {
    // rvec[c] = sum_o Wk[o][c]*bq[o] — 8 independent accumulators so 8
    // column loads are in flight per latency round (was 1; ~40 us tail).
    const int c0 = (id - 768) * 64;
    const int lane = t & 63, wave = t >> 6;
    const int c = c0 + lane;
    const float* wkcol = wq + (size_t)NC * NC + c;  // Wk[o][c], stride NC
    float a8[8] = {0.f, 0.f, 0.f, 0.f, 0.f, 0.f, 0.f, 0.f};
#pragma unroll
    for (int k = 0; k < 16; ++k) {
      const int ob = wave * 128 + k * 8;
#pragma unroll
      for (int u = 0; u < 8; ++u)
        a8[u] += wkcol[(size_t)(ob + u) * NC] * bqkv[ob + u];
    }
    float s = ((a8[0] + a8[1]) + (a8[2] + a8[3])) + ((a8[4] + a8[5]) + (a8[6] + a8[7]));
    float* red = (float*)smem;
    red[wave * 64 + lane] = s;
    __syncthreads();
    if (wave == 0) {
      float tot = red[lane] + red[64 + lane] + red[128 + lane] + red[192 + lane];
      rvec[c] = tot;
    }
  } else if (id < 784) {
    const int o = (id - 776) * 64 + (t >> 2);
    const int q = t & 3;
    const float4* wr = (const float4*)(wo + (size_t)o * NC + q * 128);
    const float4* bv = (const float4*)(bqkv + 2 * NC + q * 128);
    float s = 0.f;
#pragma unroll
    for (int i = 0; i < 32; ++i) {
      float4 w4 = wr[i], b4 = bv[i];
      s += (w4.x * b4.x + w4.y * b4.y) + (w4.z * b4.z + w4.w * b4.w);
    }
    s += __shfl_xor(s, 1);
    s += __shfl_xor(s, 2);
    if (q == 0) bc[o] = s;
  } else {
    // zero rowsum (4 blocks) then R (4 blocks) — ws is NOT re-poisoned
    // between timed replays, so both must be zeroed every call.
    const int z = id - 784;
    float* tgt = (z < 4) ? (rowsum + z * 4096) : (R + (z - 4) * 4096);
    float4* dst = (float4*)tgt;
#pragma unroll
    for (int i = 0; i < 4; ++i) dst[i * 256 + t] = make_float4(0.f, 0.f, 0.f, 0.f);
  }
}

// ---------------------------------------------------------------------------
// SINGLE-BUFFERED m97-exact BK=64 core (r14-proven), templated on MROWS.
// B-tile fixed 128 rows. 4 blocks/CU; per-tile vmcnt(0) drain hidden by
// cross-block overlap. 0-conflict XOR swizzle.
// ---------------------------------------------------------------------------
template <int MROWS>
__device__ __forceinline__ void stage_pair(const __bf16* __restrict__ A, int lda,
                                           const __bf16* __restrict__ B, int ldb,
                                           int k0, __bf16* lAf, __bf16* lBf) {
  const int tid = threadIdx.x;
#pragma unroll
  for (int i = 0; i < 4; ++i) {
    const int idx = tid + i * 256;
    const int srow = idx >> 3;
    const int ss = ((idx & 7) ^ (srow & 7)) * 8;
    GLDS16(B + (size_t)srow * ldb + k0 + ss, lBf + idx * 8);
  }
#pragma unroll
  for (int i = 0; i < MROWS / 32; ++i) {
    const int idx = tid + i * 256;
    const int srow = idx >> 3;
    const int ss = ((idx & 7) ^ (srow & 7)) * 8;
    GLDS16(A + (size_t)srow * lda + k0 + ss, lAf + idx * 8);
  }
}

template <int MROWS>
__device__ __forceinline__ void gemm_core_sb(const __bf16* __restrict__ A, int lda,
                                             const __bf16* __restrict__ B, int ldb,
                                             int K, __bf16 (*lA)[64],
                                             __bf16 (*lB)[64], f32x4 (*acc)[4]) {
  constexpr int MH = MROWS / 32;   // m-frags per wave
  const int tid = threadIdx.x;
  const int lane = tid & 63, wave = tid >> 6;
  const int wm = (wave >> 1) * (MROWS / 2), wn = (wave & 1) * 64;
  const int fr = lane & 15, fg = (lane >> 4) * 8;
  const int nt = K >> 6;

  for (int t = 0; t < nt; ++t) {
    stage_pair<MROWS>(A, lda, B, ldb, t * 64, &lA[0][0], &lB[0][0]);
    __syncthreads();   // drains vmcnt(0)+lgkmcnt per HIP barrier semantics
    __builtin_amdgcn_s_setprio(1);
#pragma unroll
    for (int ks = 0; ks < 2; ++ks) {
      bf16x8 af[MH], bfr[4];
#pragma unroll
      for (int mi = 0; mi < MH; ++mi) {
        const int r = wm + mi * 16 + fr;
        af[mi] = *(const bf16x8*)&lA[r][(ks * 32 + fg) ^ ((r & 7) << 3)];
      }
#pragma unroll
      for (int ni = 0; ni < 4; ++ni) {
        const int r = wn + ni * 16 + fr;
        bfr[ni] = *(const bf16x8*)&lB[r][(ks * 32 + fg) ^ ((r & 7) << 3)];
      }
#pragma unroll
      for (int mi = 0; mi < MH; ++mi)
#pragma unroll
        for (int ni = 0; ni < 4; ++ni)
          acc[mi][ni] = __builtin_amdgcn_mfma_f32_16x16x32_bf16(af[mi], bfr[ni], acc[mi][ni], 0, 0, 0);
    }
    __builtin_amdgcn_s_setprio(0);
    if (t + 1 < nt) __syncthreads();  // protect buffer before next stage
  }
}

// ===========================================================================
// K2: pack_mid — ONE launch (grid 2080):
//   id < 2048: pack: xnT[b][n][c] = bf16(GN(x)) via 64x64 LDS transpose;
//              ALSO R[b][n] += rvec . xn partial (quad-reduced, one
//              atomicAdd per n).
//   id >= 2048: 32 smallm GEMM blocks -> Aproj (M = Wq^T Wk; Wc = Wout Wv).
// ===========================================================================
__global__ __launch_bounds__(256, 4) void pack_mid_kernel(
    const float* __restrict__ x, const float* __restrict__ coefA,
    const float* __restrict__ coefB, const float* __restrict__ rvec,
    const __bf16* __restrict__ wqT, const __bf16* __restrict__ wkT,
    const __bf16* __restrict__ wvT, const __bf16* __restrict__ wob,
    __bf16* __restrict__ xnT, float* __restrict__ R,
    __bf16* __restrict__ Aproj) {
  __shared__ __align__(16) __bf16 smem[2 * 128 * 64];  // 32 KB union
  const int id = blockIdx.x;
  const int tid = threadIdx.x;
  if (id < 2048) {
    const int L = (id & 7) * 256 + (id >> 3);  // XCD swizzle CPX=256 -> XCD=b/2
    const int b = L >> 7, rem = L & 127;
    const int c0 = (rem >> 4) * 64, n0 = (rem & 15) * 64;
    __bf16 (*l)[72] = (__bf16(*)[72])smem;     // [n][c], 9.2 KB of the union
    const int cl = tid >> 2, seg = (tid & 3) * 16;
    const float ca = coefA[b * NC + c0 + cl], cb = coefB[b * NC + c0 + cl];
    const float4* src = (const float4*)(x + (size_t)(b * NC + c0 + cl) * NSPA + n0 + seg);
#pragma unroll
    for (int i = 0; i < 4; ++i) {
      float4 v = src[i];
      l[seg + i * 4 + 0][cl] = tob(v.x * ca + cb);
      l[seg + i * 4 + 1][cl] = tob(v.y * ca + cb);
      l[seg + i * 4 + 2][cl] = tob(v.z * ca + cb);
      l[seg + i * 4 + 3][cl] = tob(v.w * ca + cb);
    }
    __syncthreads();
#pragma unroll
    for (int i = 0; i < 2; ++i) {
      const int chunk = tid + i * 256;
      const int row = chunk >> 3, s = chunk & 7;
      *(bf16x8*)(xnT + (size_t)(b * NSPA + n0 + row) * NC + c0 + s * 8) =
          *(const bf16x8*)&l[row][s * 8];
    }
    // R partial: n = tid>>2, q = tid&3 handles 16 c each; quad shfl-reduce.
    const int nn = tid >> 2, q = tid & 3;
    const float* rv = rvec + c0 + q * 16;
    float s = 0.f;
#pragma unroll
    for (int i = 0; i < 16; ++i) s += (float)l[nn][q * 16 + i] * rv[i];
    s += __shfl_xor(s, 1);
    s += __shfl_xor(s, 2);
    if (q == 0) atomicAdd(&R[b * NSPA + n0 + nn], s);
  } else {
    const int sub0 = id - 2048;
    const bool doM = sub0 < 16;
    const int sub = doM ? sub0 : sub0 - 16;
    const int mt = sub >> 2, nt2 = sub & 3;
    const __bf16* A = doM ? (wqT + (size_t)mt * 128 * NC) : (wob + (size_t)mt * 128 * NC);
    const __bf16* B = doM ? (wkT + (size_t)nt2 * 128 * NC) : (wvT + (size_t)nt2 * 128 * NC);
    __bf16 (*lA)[64] = (__bf16(*)[64])smem;
    __bf16 (*lB)[64] = (__bf16(*)[64])(smem + 128 * 64);
    f32x4 acc[4][4] = {};
    gemm_core_sb<128>(A, NC, B, NC, NC, lA, lB, acc);

    const int lane = tid & 63, wave = tid >> 6;
    const int wm = (wave >> 1) * 64, wn = (wave & 1) * 64;
    const int fr = lane & 15, fq4 = (lane >> 4) * 4;
    const int mbase = (doM ? 0 : NC) + mt * 128;
#pragma unroll
    for (int mi = 0; mi < 4; ++mi) {
      const int m = mbase + wm + mi * 16 + fq4;
#pragma unroll
      for (int ni = 0; ni < 4; ++ni) {
        const int n = nt2 * 128 + wn + ni * 16 + fr;
#pragma unroll
        for (int r = 0; r < 4; ++r)
          Aproj[(size_t)(m + r) * NC + n] = tob(acc[mi][ni][r]);
      }
    }
  }
}

// ---------------------------------------------------------------------------
// K3: proj GEMM. C[m][n=(b,j)] = Aproj[m][:] . xn_j
//   m <  512: transposed store -> Yt[b][j][c]
//   m >= 512: natural store -> v'[b][d][j] + bc[d]
// grid 1024 (CPX=128 -> XCD=b/2); 4 blocks/CU -> whole grid co-resident.
// ---------------------------------------------------------------------------
__global__ __launch_bounds__(256, 4) void proj_kernel(
    const __bf16* __restrict__ Aproj, const __bf16* __restrict__ xnT,
    const float* __restrict__ bc, __bf16* __restrict__ Yt, __bf16* __restrict__ vp) {
  const int L = xcd_swz(128);
  const int pair = L >> 3, mblk = L & 7;
  const int b = pair >> 3;
  const int n0 = (pair & 7) * 128, m0 = mblk * 128;
  __shared__ __bf16 lA[128][64], lB[128][64];
  f32x4 acc[4][4] = {};
  gemm_core_sb<128>(Aproj + (size_t)m0 * NC, NC, xnT + ((size_t)b * NSPA + n0) * NC, NC,
                    NC, lA, lB, acc);

  const int lane = threadIdx.x & 63, wave = threadIdx.x >> 6;
  const int wm = (wave >> 1) * 64, wn = (wave & 1) * 64;
  const int fr = lane & 15, fq4 = (lane >> 4) * 4;
  if (m0 < NC) {  // Y path: transposed store
#pragma unroll
    for (int mi = 0; mi < 4; ++mi) {
      const int m = m0 + wm + mi * 16 + fq4;
#pragma unroll
      for (int ni = 0; ni < 4; ++ni) {
        const int n = n0 + wn + ni * 16 + fr;
        bf16x4 w;
        w[0] = tob(acc[mi][ni][0]);
        w[1] = tob(acc[mi][ni][1]);
        w[2] = tob(acc[mi][ni][2]);
        w[3] = tob(acc[mi][ni][3]);
        *(bf16x4*)(Yt + ((size_t)b * NSPA + n) * NC + m) = w;
      }
    }
  } else {  // v' path: natural store + bc
#pragma unroll
    for (int mi = 0; mi < 4; ++mi) {
      const int m = m0 + wm + mi * 16 + fq4;
      const int d = m - NC;
      const float4 bias = *(const float4*)(bc + d);
#pragma unroll
      for (int ni = 0; ni < 4; ++ni) {
        const int n = n0 + wn + ni * 16 + fr;
        vp[((size_t)b * NC + d + 0) * NSPA + n] = tob(acc[mi][ni][0] + bias.x);
        vp[((size_t)b * NC + d + 1) * NSPA + n] = tob(acc[mi][ni][1] + bias.y);
        vp[((size_t)b * NC + d + 2) * NSPA + n] = tob(acc[mi][ni][2] + bias.z);
        vp[((size_t)b * NC + d + 3) * NSPA + n] = tob(acc[mi][ni][3] + bias.w);
      }
    }
  }
}

// ---------------------------------------------------------------------------
// K4: scores + exp + rowsum (unnormalized exp; softmax pass deleted).
// grid 1024 (CPX=128 -> XCD=b/2); 4 blocks/CU.
// ---------------------------------------------------------------------------
__global__ __launch_bounds__(256, 4) void scores_kernel(
    const __bf16* __restrict__ Yt, const __bf16* __restrict__ xnT,
    const float* __restrict__ R, __bf16* __restrict__ P,
    float* __restrict__ rowsum) {
  const int L = xcd_swz(128);
  const int b = L >> 6, r = L & 63;
  const int i0 = (r >> 3) * 128, j0 = (r & 7) * 128;
  __shared__ __bf16 lA[128][64], lB[128][64];
  f32x4 acc[4][4] = {};
  gemm_core_sb<128>(Yt + ((size_t)b * NSPA + j0) * NC, NC,
                    xnT + ((size_t)b * NSPA + i0) * NC, NC, NC, lA, lB, acc);

  const int lane = threadIdx.x & 63, wave = threadIdx.x >> 6;
  const int wm = (wave >> 1) * 64, wn = (wave & 1) * 64;
  const int fr = lane & 15, fq4 = (lane >> 4) * 4;
  float rsum[4] = {0.f, 0.f, 0.f, 0.f};
#pragma unroll
  for (int mi = 0; mi < 4; ++mi) {
    const int j = j0 + wm + mi * 16 + fq4;
    const float4 Rb = *(const float4*)(R + b * NSPA + j);
#pragma unroll
    for (int ni = 0; ni < 4; ++ni) {
      const int i = i0 + wn + ni * 16 + fr;
      bf16x4 w;
      w[0] = tob(__expf((acc[mi][ni][0] + Rb.x) * SCL));
      w[1] = tob(__expf((acc[mi][ni][1] + Rb.y) * SCL));
      w[2] = tob(__expf((acc[mi][ni][2] + Rb.z) * SCL));
      w[3] = tob(__expf((acc[mi][ni][3] + Rb.w) * SCL));
      rsum[ni] += ((float)w[0] + (float)w[1]) + ((float)w[2] + (float)w[3]);
      *(bf16x4*)(P + ((size_t)b * NSPA + i) * NSPA + j) = w;
    }
  }
#pragma unroll
  for (int ni = 0; ni < 4; ++ni) {
    rsum[ni] += __shfl_xor(rsum[ni], 16);
    rsum[ni] += __shfl_xor(rsum[ni], 32);
  }
  if (lane < 16) {
#pragma unroll
    for (int ni = 0; ni < 4; ++ni)
      atomicAdd(&rowsum[b * NSPA + i0 + wn + ni * 16 + fr], rsum[ni]);
  }
}

// ---------------------------------------------------------------------------
// K5: PV + normalize + out fused, 64-row d-tiles -> grid 1024 co-resident.
// C[d][i] = v'[d][:] . P[i][:] (K=1024); out = C/rowsum + bout + x (fp32).
// grid 1024 (CPX=128 -> XCD=b/2)
// ---------------------------------------------------------------------------
__global__ __launch_bounds__(256, 4) void pvout_kernel(
    const __bf16* __restrict__ vp, const __bf16* __restrict__ P,
    const float* __restrict__ rowsum, const float* __restrict__ bout,
    const float* __restrict__ x, float* __restrict__ out) {
  const int L = xcd_swz(128);
  const int b = L >> 6, r = L & 63;
  const int d0 = (r >> 3) * 64, i0 = (r & 7) * 128;
  __shared__ __bf16 lA[64][64], lB[128][64];
  f32x4 acc[2][4] = {};
  gemm_core_sb<64>(vp + ((size_t)b * NC + d0) * NSPA, NSPA,
                   P + ((size_t)b * NSPA + i0) * NSPA, NSPA, NSPA, lA, lB, acc);

  const int lane = threadIdx.x & 63, wave = threadIdx.x >> 6;
  const int wm = (wave >> 1) * 32, wn = (wave & 1) * 64;
  const int fr = lane & 15, fq4 = (lane >> 4) * 4;
  float inv[4];
#pragma unroll
  for (int ni = 0; ni < 4; ++ni)
    inv[ni] = 1.f / rowsum[b * NSPA + i0 + wn + ni * 16 + fr];
#pragma unroll
  for (int mi = 0; mi < 2; ++mi) {
    const int d = d0 + wm + mi * 16 + fq4;
    const float4 bias = *(const float4*)(bout + d);
#pragma unroll
    for (int ni = 0; ni < 4; ++ni) {
      const int i = i0 + wn + ni * 16 + fr;
      const size_t ix = ((size_t)b * NC + d) * NSPA + i;
      out[ix + 0 * NSPA] = acc[mi][ni][0] * inv[ni] + bias.x + x[ix + 0 * NSPA];
      out[ix + 1 * NSPA] = acc[mi][ni][1] * inv[ni] + bias.y + x[ix + 1 * NSPA];
      out[ix + 2 * NSPA] = acc[mi][ni][2] * inv[ni] + bias.z + x[ix + 2 * NSPA];
      out[ix + 3 * NSPA] = acc[mi][ni][3] * inv[ni] + bias.w + x[ix + 3 * NSPA];
    }
  }
}

// ---------------------------------------------------------------------------
// Workspace (~67 MB):
//   coefA/B 64KB | rvec/bc 4KB | R 64KB | rowsum 64KB | wqT/wkT/wvT/wob 2MB
//   Aproj 1MB | xnT 16MB | v' 16MB | P 32MB.  Yt (16MB) lives in d_out.
// ---------------------------------------------------------------------------
extern "C" void kernel_launch(void* const* d_in, const int* in_sizes, int n_in,
                              void* d_out, int out_size, void* d_ws, size_t ws_size,
                              hipStream_t stream) {
  const float* x        = (const float*)d_in[0];
  const float* gn_scale = (const float*)d_in[3];
  const float* gn_bias  = (const float*)d_in[4];
  const float* w_qkv    = (const float*)d_in[5];
  const float* b_qkv    = (const float*)d_in[6];
  const float* w_out    = (const float*)d_in[7];
  const float* b_out    = (const float*)d_in[8];
  float* out = (float*)d_out;

  float*  coefA  = (float*)d_ws;                 // 8192
  float*  coefB  = coefA + NB * NC;              // 8192
  float*  rvec   = coefB + NB * NC;              // 512
  float*  bc     = rvec + NC;                    // 512
  float*  R      = bc + NC;                      // 16384
  float*  rowsum = R + NB * NSPA;                // 16384
  __bf16* wqT    = (__bf16*)(rowsum + NB * NSPA);
  __bf16* wkT    = wqT + NC * NC;
  __bf16* wvT    = wkT + NC * NC;
  __bf16* wob    = wvT + NC * NC;
  __bf16* Aproj  = wob + NC * NC;                // 1024x512
  __bf16* xnT    = Aproj + 2 * NC * NC;          // 8M elems
  __bf16* vp     = xnT + (size_t)NB * NSPA * NC; // 8M elems
  __bf16* P      = vp + (size_t)NB * NC * NSPA;  // 16M elems
  __bf16* Yt     = (__bf16*)d_out;               // 16MB scratch in d_out

  stats_w_kernel<<<dim3(792), 256, 0, stream>>>(x, gn_scale, gn_bias, w_qkv, w_out,
                                                b_qkv, coefA, coefB, wqT, wkT, wvT,
                                                wob, rvec, bc, rowsum, R);
  pack_mid_kernel<<<dim3(2080), 256, 0, stream>>>(x, coefA, coefB, rvec, wqT, wkT,
                                                  wvT, wob, xnT, R, Aproj);
  proj_kernel<<<dim3(1024), 256, 0, stream>>>(Aproj, xnT, bc, Yt, vp);
  scores_kernel<<<dim3(1024), 256, 0, stream>>>(Yt, xnT, R, P, rowsum);
  pvout_kernel<<<dim3(1024), 256, 0, stream>>>(vp, P, rowsum, b_out, x, out);
}

// Round 18
// 108.783 us; speedup vs baseline: 1.3159x; 1.0161x over previous
//
#include <hip/hip_runtime.h>
#include <hip/hip_bf16.h>

// Shapes (fixed by the problem)
#define NB   16    // batch
#define NC   512   // channels
#define NSPA 1024  // h*w
#define GN_EPS 1e-5f
#define SCL 0.044194173824159216f  // 512^-0.5

typedef __bf16 bf16x8 __attribute__((ext_vector_type(8)));
typedef __bf16 bf16x4 __attribute__((ext_vector_type(4)));
typedef float  f32x4  __attribute__((ext_vector_type(4)));

typedef __attribute__((address_space(3))) void lds_t;
typedef const __attribute__((address_space(1))) void gl_t;
#define GLDS16(g, l) __builtin_amdgcn_global_load_lds((gl_t*)(g), (lds_t*)(l), 16, 0, 0)

__device__ __forceinline__ __bf16 tob(float f) { return (__bf16)f; }

// Bijective XCD-chunk swizzle (T1): each XCD gets a contiguous logical chunk.
__device__ __forceinline__ int xcd_swz(int cpx) {
  return (blockIdx.x & 7) * cpx + (blockIdx.x >> 3);
}

// ===========================================================================
// K1: stats_w — lightweight heterogeneous blocks (grid 792):
//   id <  512 : GN stats ONLY -> coefA/coefB
//   id <  704 : 64x64 transpose tiles wqT/wkT/wvT[c][o] bf16  (192 blocks)
//   id <  768 : pack Wout natural -> wob bf16                  (64 blocks)
//   id <  776 : rvec[c] = sum_o Wk[o][c]*bq[o]  (8-way ILP)
//   id <  784 : bc[o]   = sum_c Wout[o][c]*bv[c]               (8 blocks)
//   id <  792 : zero rowsum[16384] + R[16384] (every call)     (8 blocks)
// ===========================================================================
__global__ void stats_w_kernel(const float* __restrict__ x,
                               const float* __restrict__ gn_scale,
                               const float* __restrict__ gn_bias,
                               const float* __restrict__ wq,   // w_qkv [1536][512]
                               const float* __restrict__ wo,   // w_out [512][512]
                               const float* __restrict__ bqkv, // [1536]
                               float* __restrict__ coefA, float* __restrict__ coefB,
                               __bf16* __restrict__ wqT, __bf16* __restrict__ wkT,
                               __bf16* __restrict__ wvT, __bf16* __restrict__ wob,
                               float* __restrict__ rvec, float* __restrict__ bc,
                               float* __restrict__ rowsum, float* __restrict__ R) {
  __shared__ __align__(16) unsigned char smem[9216];
  const int id = blockIdx.x;
  const int t = threadIdx.x;
  if (id < 512) {
    const int L = (id & 7) * 64 + (id >> 3);   // XCD-chunk swizzle (CPX=64)
    const int b = L >> 5, g = L & 31;
    const float4* base = (const float4*)(x + (size_t)(b * NC + g * 16) * NSPA);
    float s = 0.f, ss = 0.f;
#pragma unroll
    for (int i = 0; i < 16; ++i) {
      float4 v = base[i * 256 + t];
      s  += (v.x + v.y) + (v.z + v.w);
      ss += (v.x * v.x + v.y * v.y) + (v.z * v.z + v.w * v.w);
    }
#pragma unroll
    for (int off = 32; off; off >>= 1) {
      s  += __shfl_xor(s, off);
      ss += __shfl_xor(ss, off);
    }
    float* red = (float*)smem;
    const int wave = t >> 6, lane = t & 63;
    if (lane == 0) { red[wave] = s; red[4 + wave] = ss; }
    __syncthreads();
    if (t < 16) {
      const float S  = red[0] + red[1] + red[2] + red[3];
      const float SS = red[4] + red[5] + red[6] + red[7];
      const float mean = S * (1.f / 16384.f);
      const float var  = SS * (1.f / 16384.f) - mean * mean;
      const float rstd = rsqrtf(var + GN_EPS);
      const int c = g * 16 + t;
      const float a = gn_scale[c] * rstd;
      coefA[b * NC + c] = a;
      coefB[b * NC + c] = gn_bias[c] - mean * a;
    }
  } else if (id < 704) {
    const int id2 = id - 512;
    const int mat = id2 >> 6, tile = id2 & 63;
    const int o0 = (tile >> 3) * 64, c0 = (tile & 7) * 64;
    __bf16* dstT = (mat == 0) ? wqT : (mat == 1) ? wkT : wvT;
    __bf16 (*l)[72] = (__bf16(*)[72])smem;
    const int orr = t >> 2, seg = (t & 3) * 16;
    const float4* src = (const float4*)(wq + (size_t)(mat * NC + o0 + orr) * NC + c0 + seg);
#pragma unroll
    for (int i = 0; i < 4; ++i) {
      float4 v = src[i];
      l[seg + i * 4 + 0][orr] = tob(v.x);
      l[seg + i * 4 + 1][orr] = tob(v.y);
      l[seg + i * 4 + 2][orr] = tob(v.z);
      l[seg + i * 4 + 3][orr] = tob(v.w);
    }
    __syncthreads();
#pragma unroll
    for (int i = 0; i < 2; ++i) {
      const int chunk = t + i * 256;
      const int row = chunk >> 3, sg = chunk & 7;
      *(bf16x8*)(dstT + (size_t)(c0 + row) * NC + o0 + sg * 8) = *(const bf16x8*)&l[row][sg * 8];
    }
  } else if (id < 768) {
    const int idx = id - 704;
#pragma unroll
    for (int i = 0; i < 4; ++i) {
      const int tt = idx * 1024 + i * 256 + t;
      float4 v = ((const float4*)wo)[tt];
      bf16x4 w;
      w[0] = tob(v.x); w[1] = tob(v.y); w[2] = tob(v.z); w[3] = tob(v.w);
      *(bf16x4*)(wob + (size_t)tt * 4) = w;
    }
  } else if (id < 776) {
    // rvec[c] = sum_o Wk[o][c]*bq[o] — 8 independent accumulators (ILP).
    const int c0 = (id - 768) * 64;
    const int lane = t & 63, wave = t >> 6;
    const int c = c0 + lane;
    const float* wkcol = wq + (size_t)NC * NC + c;  // Wk[o][c], stride NC
    float a8[8] = {0.f, 0.f, 0.f, 0.f, 0.f, 0.f, 0.f, 0.f};
#pragma unroll
    for (int k = 0; k < 16; ++k) {
      const int ob = wave * 128 + k * 8;
#pragma unroll
      for (int u = 0; u < 8; ++u)
        a8[u] += wkcol[(size_t)(ob + u) * NC] * bqkv[ob + u];
    }
    float s = ((a8[0] + a8[1]) + (a8[2] + a8[3])) + ((a8[4] + a8[5]) + (a8[6] + a8[7]));
    float* red = (float*)smem;
    red[wave * 64 + lane] = s;
    __syncthreads();
    if (wave == 0) {
      float tot = red[lane] + red[64 + lane] + red[128 + lane] + red[192 + lane];
      rvec[c] = tot;
    }
  } else if (id < 784) {
    const int o = (id - 776) * 64 + (t >> 2);
    const int q = t & 3;
    const float4* wr = (const float4*)(wo + (size_t)o * NC + q * 128);
    const float4* bv = (const float4*)(bqkv + 2 * NC + q * 128);
    float s = 0.f;
#pragma unroll
    for (int i = 0; i < 32; ++i) {
      float4 w4 = wr[i], b4 = bv[i];
      s += (w4.x * b4.x + w4.y * b4.y) + (w4.z * b4.z + w4.w * b4.w);
    }
    s += __shfl_xor(s, 1);
    s += __shfl_xor(s, 2);
    if (q == 0) bc[o] = s;
  } else {
    // zero rowsum (4 blocks) then R (4 blocks) — every call (no re-poison).
    const int z = id - 784;
    float* tgt = (z < 4) ? (rowsum + z * 4096) : (R + (z - 4) * 4096);
    float4* dst = (float4*)tgt;
#pragma unroll
    for (int i = 0; i < 4; ++i) dst[i * 256 + t] = make_float4(0.f, 0.f, 0.f, 0.f);
  }
}

// ---------------------------------------------------------------------------
// SINGLE-BUFFERED m97-exact BK=64 core (r14-proven), templated on MROWS
// (A-tile rows: 256/128/64). B-tile fixed 128 rows. Per-tile vmcnt(0) drain
// hidden by cross-block overlap; 0-conflict XOR swizzle.
// MROWS=256 raises MFMA-per-staged-byte by 33% (64 MFMA/wave per tile on
// 48 KB) — attacks the stage-bound regime identified in r17.
// ---------------------------------------------------------------------------
template <int MROWS>
__device__ __forceinline__ void stage_pair(const __bf16* __restrict__ A, int lda,
                                           const __bf16* __restrict__ B, int ldb,
                                           int k0, __bf16* lAf, __bf16* lBf) {
  const int tid = threadIdx.x;
#pragma unroll
  for (int i = 0; i < 4; ++i) {
    const int idx = tid + i * 256;
    const int srow = idx >> 3;
    const int ss = ((idx & 7) ^ (srow & 7)) * 8;
    GLDS16(B + (size_t)srow * ldb + k0 + ss, lBf + idx * 8);
  }
#pragma unroll
  for (int i = 0; i < MROWS / 32; ++i) {
    const int idx = tid + i * 256;
    const int srow = idx >> 3;
    const int ss = ((idx & 7) ^ (srow & 7)) * 8;
    GLDS16(A + (size_t)srow * lda + k0 + ss, lAf + idx * 8);
  }
}

template <int MROWS>
__device__ __forceinline__ void gemm_core_sb(const __bf16* __restrict__ A, int lda,
                                             const __bf16* __restrict__ B, int ldb,
                                             int K, __bf16 (*lA)[64],
                                             __bf16 (*lB)[64], f32x4 (*acc)[4]) {
  constexpr int MH = MROWS / 32;   // m-frags per wave
  const int tid = threadIdx.x;
  const int lane = tid & 63, wave = tid >> 6;
  const int wm = (wave >> 1) * (MROWS / 2), wn = (wave & 1) * 64;
  const int fr = lane & 15, fg = (lane >> 4) * 8;
  const int nt = K >> 6;

  for (int t = 0; t < nt; ++t) {
    stage_pair<MROWS>(A, lda, B, ldb, t * 64, &lA[0][0], &lB[0][0]);
    __syncthreads();   // drains vmcnt(0)+lgkmcnt per HIP barrier semantics
    __builtin_amdgcn_s_setprio(1);
#pragma unroll
    for (int ks = 0; ks < 2; ++ks) {
      bf16x8 af[MH], bfr[4];
#pragma unroll
      for (int mi = 0; mi < MH; ++mi) {
        const int r = wm + mi * 16 + fr;
        af[mi] = *(const bf16x8*)&lA[r][(ks * 32 + fg) ^ ((r & 7) << 3)];
      }
#pragma unroll
      for (int ni = 0; ni < 4; ++ni) {
        const int r = wn + ni * 16 + fr;
        bfr[ni] = *(const bf16x8*)&lB[r][(ks * 32 + fg) ^ ((r & 7) << 3)];
      }
#pragma unroll
      for (int mi = 0; mi < MH; ++mi)
#pragma unroll
        for (int ni = 0; ni < 4; ++ni)
          acc[mi][ni] = __builtin_amdgcn_mfma_f32_16x16x32_bf16(af[mi], bfr[ni], acc[mi][ni], 0, 0, 0);
    }
    __builtin_amdgcn_s_setprio(0);
    if (t + 1 < nt) __syncthreads();  // protect buffer before next stage
  }
}

// ===========================================================================
// K2: pack_mid — ONE launch (grid 2080):
//   id < 2048: pack: xnT[b][n][c] = bf16(GN(x)) via 64x64 LDS transpose;
//              ALSO R[b][n] += rvec . xn partial (quad-reduced atomicAdd).
//   id >= 2048: 32 smallm GEMM blocks -> Aproj (M = Wq^T Wk; Wc = Wout Wv).
// ===========================================================================
__global__ __launch_bounds__(256, 4) void pack_mid_kernel(
    const float* __restrict__ x, const float* __restrict__ coefA,
    const float* __restrict__ coefB, const float* __restrict__ rvec,
    const __bf16* __restrict__ wqT, const __bf16* __restrict__ wkT,
    const __bf16* __restrict__ wvT, const __bf16* __restrict__ wob,
    __bf16* __restrict__ xnT, float* __restrict__ R,
    __bf16* __restrict__ Aproj) {
  __shared__ __align__(16) __bf16 smem[2 * 128 * 64];  // 32 KB union
  const int id = blockIdx.x;
  const int tid = threadIdx.x;
  if (id < 2048) {
    const int L = (id & 7) * 256 + (id >> 3);  // XCD swizzle CPX=256 -> XCD=b/2
    const int b = L >> 7, rem = L & 127;
    const int c0 = (rem >> 4) * 64, n0 = (rem & 15) * 64;
    __bf16 (*l)[72] = (__bf16(*)[72])smem;     // [n][c], 9.2 KB of the union
    const int cl = tid >> 2, seg = (tid & 3) * 16;
    const float ca = coefA[b * NC + c0 + cl], cb = coefB[b * NC + c0 + cl];
    const float4* src = (const float4*)(x + (size_t)(b * NC + c0 + cl) * NSPA + n0 + seg);
#pragma unroll
    for (int i = 0; i < 4; ++i) {
      float4 v = src[i];
      l[seg + i * 4 + 0][cl] = tob(v.x * ca + cb);
      l[seg + i * 4 + 1][cl] = tob(v.y * ca + cb);
      l[seg + i * 4 + 2][cl] = tob(v.z * ca + cb);
      l[seg + i * 4 + 3][cl] = tob(v.w * ca + cb);
    }
    __syncthreads();
#pragma unroll
    for (int i = 0; i < 2; ++i) {
      const int chunk = tid + i * 256;
      const int row = chunk >> 3, s = chunk & 7;
      *(bf16x8*)(xnT + (size_t)(b * NSPA + n0 + row) * NC + c0 + s * 8) =
          *(const bf16x8*)&l[row][s * 8];
    }
    const int nn = tid >> 2, q = tid & 3;
    const float* rv = rvec + c0 + q * 16;
    float s = 0.f;
#pragma unroll
    for (int i = 0; i < 16; ++i) s += (float)l[nn][q * 16 + i] * rv[i];
    s += __shfl_xor(s, 1);
    s += __shfl_xor(s, 2);
    if (q == 0) atomicAdd(&R[b * NSPA + n0 + nn], s);
  } else {
    const int sub0 = id - 2048;
    const bool doM = sub0 < 16;
    const int sub = doM ? sub0 : sub0 - 16;
    const int mt = sub >> 2, nt2 = sub & 3;
    const __bf16* A = doM ? (wqT + (size_t)mt * 128 * NC) : (wob + (size_t)mt * 128 * NC);
    const __bf16* B = doM ? (wkT + (size_t)nt2 * 128 * NC) : (wvT + (size_t)nt2 * 128 * NC);
    __bf16 (*lA)[64] = (__bf16(*)[64])smem;
    __bf16 (*lB)[64] = (__bf16(*)[64])(smem + 128 * 64);
    f32x4 acc[4][4] = {};
    gemm_core_sb<128>(A, NC, B, NC, NC, lA, lB, acc);

    const int lane = tid & 63, wave = tid >> 6;
    const int wm = (wave >> 1) * 64, wn = (wave & 1) * 64;
    const int fr = lane & 15, fq4 = (lane >> 4) * 4;
    const int mbase = (doM ? 0 : NC) + mt * 128;
#pragma unroll
    for (int mi = 0; mi < 4; ++mi) {
      const int m = mbase + wm + mi * 16 + fq4;
#pragma unroll
      for (int ni = 0; ni < 4; ++ni) {
        const int n = nt2 * 128 + wn + ni * 16 + fr;
#pragma unroll
        for (int r = 0; r < 4; ++r)
          Aproj[(size_t)(m + r) * NC + n] = tob(acc[mi][ni][r]);
      }
    }
  }
}

// ---------------------------------------------------------------------------
// K3: proj GEMM (MROWS=256, 48 KB LDS, 2 blocks/CU).
// C[m][n=(b,j)] = Aproj[m][:] . xn_j
//   m-tile 0..1 (< 512): transposed store -> Yt[b][j][c]
//   m-tile 2..3 (>=512): natural store -> v'[b][d][j] + bc[d]
// grid 512 (CPX=64 -> XCD = L/64 = pair/16 = b/2): pair=L>>2, mblk=L&3.
// ---------------------------------------------------------------------------
__global__ __launch_bounds__(256, 2) void proj_kernel(
    const __bf16* __restrict__ Aproj, const __bf16* __restrict__ xnT,
    const float* __restrict__ bc, __bf16* __restrict__ Yt, __bf16* __restrict__ vp) {
  const int L = xcd_swz(64);
  const int pair = L >> 2, mblk = L & 3;
  const int b = pair >> 3;
  const int n0 = (pair & 7) * 128, m0 = mblk * 256;
  __shared__ __bf16 lA[256][64], lB[128][64];
  f32x4 acc[8][4] = {};
  gemm_core_sb<256>(Aproj + (size_t)m0 * NC, NC, xnT + ((size_t)b * NSPA + n0) * NC, NC,
                    NC, lA, lB, acc);

  const int lane = threadIdx.x & 63, wave = threadIdx.x >> 6;
  const int wm = (wave >> 1) * 128, wn = (wave & 1) * 64;
  const int fr = lane & 15, fq4 = (lane >> 4) * 4;
  if (m0 < NC) {  // Y path: transposed store
#pragma unroll
    for (int mi = 0; mi < 8; ++mi) {
      const int m = m0 + wm + mi * 16 + fq4;
#pragma unroll
      for (int ni = 0; ni < 4; ++ni) {
        const int n = n0 + wn + ni * 16 + fr;
        bf16x4 w;
        w[0] = tob(acc[mi][ni][0]);
        w[1] = tob(acc[mi][ni][1]);
        w[2] = tob(acc[mi][ni][2]);
        w[3] = tob(acc[mi][ni][3]);
        *(bf16x4*)(Yt + ((size_t)b * NSPA + n) * NC + m) = w;
      }
    }
  } else {  // v' path: natural store + bc
#pragma unroll
    for (int mi = 0; mi < 8; ++mi) {
      const int m = m0 + wm + mi * 16 + fq4;
      const int d = m - NC;
      const float4 bias = *(const float4*)(bc + d);
#pragma unroll
      for (int ni = 0; ni < 4; ++ni) {
        const int n = n0 + wn + ni * 16 + fr;
        vp[((size_t)b * NC + d + 0) * NSPA + n] = tob(acc[mi][ni][0] + bias.x);
        vp[((size_t)b * NC + d + 1) * NSPA + n] = tob(acc[mi][ni][1] + bias.y);
        vp[((size_t)b * NC + d + 2) * NSPA + n] = tob(acc[mi][ni][2] + bias.z);
        vp[((size_t)b * NC + d + 3) * NSPA + n] = tob(acc[mi][ni][3] + bias.w);
      }
    }
  }
}

// ---------------------------------------------------------------------------
// K4: scores + exp + rowsum (MROWS=256 j-tiles, 48 KB LDS, 2 blocks/CU).
// grid 512 (CPX=32... using CPX=64: b = L>>5 -> XCD = b/2): r=L&31,
// i0=(r>>2)*128, j0=(r&3)*256.
// ---------------------------------------------------------------------------
__global__ __launch_bounds__(256, 2) void scores_kernel(
    const __bf16* __restrict__ Yt, const __bf16* __restrict__ xnT,
    const float* __restrict__ R, __bf16* __restrict__ P,
    float* __restrict__ rowsum) {
  const int L = xcd_swz(64);
  const int b = L >> 5, r = L & 31;
  const int i0 = (r >> 2) * 128, j0 = (r & 3) * 256;
  __shared__ __bf16 lA[256][64], lB[128][64];
  f32x4 acc[8][4] = {};
  gemm_core_sb<256>(Yt + ((size_t)b * NSPA + j0) * NC, NC,
                    xnT + ((size_t)b * NSPA + i0) * NC, NC, NC, lA, lB, acc);

  const int lane = threadIdx.x & 63, wave = threadIdx.x >> 6;
  const int wm = (wave >> 1) * 128, wn = (wave & 1) * 64;
  const int fr = lane & 15, fq4 = (lane >> 4) * 4;
  float rsum[4] = {0.f, 0.f, 0.f, 0.f};
#pragma unroll
  for (int mi = 0; mi < 8; ++mi) {
    const int j = j0 + wm + mi * 16 + fq4;
    const float4 Rb = *(const float4*)(R + b * NSPA + j);
#pragma unroll
    for (int ni = 0; ni < 4; ++ni) {
      const int i = i0 + wn + ni * 16 + fr;
      bf16x4 w;
      w[0] = tob(__expf((acc[mi][ni][0] + Rb.x) * SCL));
      w[1] = tob(__expf((acc[mi][ni][1] + Rb.y) * SCL));
      w[2] = tob(__expf((acc[mi][ni][2] + Rb.z) * SCL));
      w[3] = tob(__expf((acc[mi][ni][3] + Rb.w) * SCL));
      rsum[ni] += ((float)w[0] + (float)w[1]) + ((float)w[2] + (float)w[3]);
      *(bf16x4*)(P + ((size_t)b * NSPA + i) * NSPA + j) = w;
    }
  }
#pragma unroll
  for (int ni = 0; ni < 4; ++ni) {
    rsum[ni] += __shfl_xor(rsum[ni], 16);
    rsum[ni] += __shfl_xor(rsum[ni], 32);
  }
  if (lane < 16) {
#pragma unroll
    for (int ni = 0; ni < 4; ++ni)
      atomicAdd(&rowsum[b * NSPA + i0 + wn + ni * 16 + fr], rsum[ni]);
  }
}

// ---------------------------------------------------------------------------
// K5: PV + normalize + out fused, 64-row d-tiles -> grid 1024 co-resident.
// C[d][i] = v'[d][:] . P[i][:] (K=1024); out = C/rowsum + bout + x (fp32).
// grid 1024 (CPX=128 -> XCD=b/2)
// ---------------------------------------------------------------------------
__global__ __launch_bounds__(256, 4) void pvout_kernel(
    const __bf16* __restrict__ vp, const __bf16* __restrict__ P,
    const float* __restrict__ rowsum, const float* __restrict__ bout,
    const float* __restrict__ x, float* __restrict__ out) {
  const int L = xcd_swz(128);
  const int b = L >> 6, r = L & 63;
  const int d0 = (r >> 3) * 64, i0 = (r & 7) * 128;
  __shared__ __bf16 lA[64][64], lB[128][64];
  f32x4 acc[2][4] = {};
  gemm_core_sb<64>(vp + ((size_t)b * NC + d0) * NSPA, NSPA,
                   P + ((size_t)b * NSPA + i0) * NSPA, NSPA, NSPA, lA, lB, acc);

  const int lane = threadIdx.x & 63, wave = threadIdx.x >> 6;
  const int wm = (wave >> 1) * 32, wn = (wave & 1) * 64;
  const int fr = lane & 15, fq4 = (lane >> 4) * 4;
  float inv[4];
#pragma unroll
  for (int ni = 0; ni < 4; ++ni)
    inv[ni] = 1.f / rowsum[b * NSPA + i0 + wn + ni * 16 + fr];
#pragma unroll
  for (int mi = 0; mi < 2; ++mi) {
    const int d = d0 + wm + mi * 16 + fq4;
    const float4 bias = *(const float4*)(bout + d);
#pragma unroll
    for (int ni = 0; ni < 4; ++ni) {
      const int i = i0 + wn + ni * 16 + fr;
      const size_t ix = ((size_t)b * NC + d) * NSPA + i;
      out[ix + 0 * NSPA] = acc[mi][ni][0] * inv[ni] + bias.x + x[ix + 0 * NSPA];
      out[ix + 1 * NSPA] = acc[mi][ni][1] * inv[ni] + bias.y + x[ix + 1 * NSPA];
      out[ix + 2 * NSPA] = acc[mi][ni][2] * inv[ni] + bias.z + x[ix + 2 * NSPA];
      out[ix + 3 * NSPA] = acc[mi][ni][3] * inv[ni] + bias.w + x[ix + 3 * NSPA];
    }
  }
}

// ---------------------------------------------------------------------------
// Workspace (~67 MB):
//   coefA/B 64KB | rvec/bc 4KB | R 64KB | rowsum 64KB | wqT/wkT/wvT/wob 2MB
//   Aproj 1MB | xnT 16MB | v' 16MB | P 32MB.  Yt (16MB) lives in d_out.
// ---------------------------------------------------------------------------
extern "C" void kernel_launch(void* const* d_in, const int* in_sizes, int n_in,
                              void* d_out, int out_size, void* d_ws, size_t ws_size,
                              hipStream_t stream) {
  const float* x        = (const float*)d_in[0];
  const float* gn_scale = (const float*)d_in[3];
  const float* gn_bias  = (const float*)d_in[4];
  const float* w_qkv    = (const float*)d_in[5];
  const float* b_qkv    = (const float*)d_in[6];
  const float* w_out    = (const float*)d_in[7];
  const float* b_out    = (const float*)d_in[8];
  float* out = (float*)d_out;

  float*  coefA  = (float*)d_ws;                 // 8192
  float*  coefB  = coefA + NB * NC;              // 8192
  float*  rvec   = coefB + NB * NC;              // 512
  float*  bc     = rvec + NC;                    // 512
  float*  R      = bc + NC;                      // 16384
  float*  rowsum = R + NB * NSPA;                // 16384
  __bf16* wqT    = (__bf16*)(rowsum + NB * NSPA);
  __bf16* wkT    = wqT + NC * NC;
  __bf16* wvT    = wkT + NC * NC;
  __bf16* wob    = wvT + NC * NC;
  __bf16* Aproj  = wob + NC * NC;                // 1024x512
  __bf16* xnT    = Aproj + 2 * NC * NC;          // 8M elems
  __bf16* vp     = xnT + (size_t)NB * NSPA * NC; // 8M elems
  __bf16* P      = vp + (size_t)NB * NC * NSPA;  // 16M elems
  __bf16* Yt     = (__bf16*)d_out;               // 16MB scratch in d_out

  stats_w_kernel<<<dim3(792), 256, 0, stream>>>(x, gn_scale, gn_bias, w_qkv, w_out,
                                                b_qkv, coefA, coefB, wqT, wkT, wvT,
                                                wob, rvec, bc, rowsum, R);
  pack_mid_kernel<<<dim3(2080), 256, 0, stream>>>(x, coefA, coefB, rvec, wqT, wkT,
                                                  wvT, wob, xnT, R, Aproj);
  proj_kernel<<<dim3(512), 256, 0, stream>>>(Aproj, xnT, bc, Yt, vp);
  scores_kernel<<<dim3(512), 256, 0, stream>>>(Yt, xnT, R, P, rowsum);
  pvout_kernel<<<dim3(1024), 256, 0, stream>>>(vp, P, rowsum, b_out, x, out);
}